// Round 1
// baseline (914.254 us; speedup 1.0000x reference)
//
#include <hip/hip_runtime.h>
#include <cstdint>
#include <cstddef>

#define NN 100000
#define NE 1600000

// ---------------- setup kernels: degree, prefix-sum (CSR), fill ----------------

__global__ __launch_bounds__(256) void k_zero(int* p, int n) {
    int i = blockIdx.x * 256 + threadIdx.x;
    if (i < n) p[i] = 0;
}

__global__ __launch_bounds__(256) void k_count(const int* __restrict__ dst, int* __restrict__ deg) {
    int e = blockIdx.x * 256 + threadIdx.x;
    if (e < NE) atomicAdd(&deg[dst[e]], 1);
}

// exclusive scan, 2048 elements per block (256 threads x 8 items)
__global__ __launch_bounds__(256) void k_scan_local(const int* __restrict__ in, int* __restrict__ out,
                                                    int* __restrict__ bsum, int n) {
    __shared__ int sh[256];
    const int tid = threadIdx.x;
    int base = blockIdx.x * 2048 + tid * 8;
    int v[8];
    int s = 0;
#pragma unroll
    for (int i = 0; i < 8; i++) {
        int idx = base + i;
        v[i] = (idx < n) ? in[idx] : 0;
        s += v[i];
    }
    sh[tid] = s;
    __syncthreads();
    for (int off = 1; off < 256; off <<= 1) {
        int t = 0;
        if (tid >= off) t = sh[tid - off];
        __syncthreads();
        sh[tid] += t;
        __syncthreads();
    }
    int excl = sh[tid] - s;
    if (tid == 255) bsum[blockIdx.x] = sh[255];
    int run = excl;
#pragma unroll
    for (int i = 0; i < 8; i++) {
        int idx = base + i;
        if (idx < n) out[idx] = run;
        run += v[i];
    }
}

__global__ void k_scan_aux(int* bsum, int nb) {
    if (blockIdx.x == 0 && threadIdx.x == 0) {
        int run = 0;
        for (int i = 0; i < nb; i++) {
            int t = bsum[i];
            bsum[i] = run;
            run += t;
        }
    }
}

__global__ __launch_bounds__(256) void k_scan_finish(int* __restrict__ row_ptr, const int* __restrict__ bsum,
                                                     int* __restrict__ cursor, const int* __restrict__ deg,
                                                     float* __restrict__ inv_deg, int n) {
    const int tid = threadIdx.x;
    int base = blockIdx.x * 2048 + tid * 8;
    int add = bsum[blockIdx.x];
#pragma unroll
    for (int i = 0; i < 8; i++) {
        int idx = base + i;
        if (idx < n) {
            int r = row_ptr[idx] + add;
            row_ptr[idx] = r;
            cursor[idx] = r;
            int d = deg[idx];
            inv_deg[idx] = (d > 0) ? 1.0f / (float)d : 0.0f;
        }
    }
    if (blockIdx.x == 0 && tid == 0) row_ptr[n] = NE;
}

__global__ __launch_bounds__(256) void k_fill(const int* __restrict__ src, const int* __restrict__ dst,
                                              int* __restrict__ cursor, int* __restrict__ col) {
    int e = blockIdx.x * 256 + threadIdx.x;
    if (e < NE) {
        int p = atomicAdd(&cursor[dst[e]], 1);
        col[p] = src[e];
    }
}

// ---------------- aggregation: one wave per destination node ----------------
// F = gathered feature count (64 or 128); LDIN = row stride of h; output row stride 128.

template <int F, int LDIN>
__global__ __launch_bounds__(256) void k_aggregate(const float* __restrict__ h, const int* __restrict__ row_ptr,
                                                   const int* __restrict__ col, const float* __restrict__ inv_deg,
                                                   float* __restrict__ agg) {
    int node = blockIdx.x * 4 + (threadIdx.x >> 6);
    int lane = threadIdx.x & 63;
    int start = row_ptr[node], end = row_ptr[node + 1];
    if (F == 64) {
        float acc = 0.f;
        for (int cs = start; cs < end; cs += 64) {
            int n = end - cs;
            if (n > 64) n = 64;
            int my = (lane < n) ? col[cs + lane] : 0;
            for (int j = 0; j < n; j++) {
                int s = __shfl(my, j);
                acc += h[(size_t)s * LDIN + lane];
            }
        }
        agg[(size_t)node * 128 + lane] = acc * inv_deg[node];
    } else {
        float accx = 0.f, accy = 0.f;
        for (int cs = start; cs < end; cs += 64) {
            int n = end - cs;
            if (n > 64) n = 64;
            int my = (lane < n) ? col[cs + lane] : 0;
            for (int j = 0; j < n; j++) {
                int s = __shfl(my, j);
                float2 v = *((const float2*)(h + (size_t)s * LDIN) + lane);
                accx += v.x;
                accy += v.y;
            }
        }
        float w = inv_deg[node];
        float2 o;
        o.x = accx * w;
        o.y = accy * w;
        *((float2*)(agg + (size_t)node * 128) + lane) = o;
    }
}

// ---------------- tiled fp32 GEMM: C[N x BN] = A[N x K] @ W[BN x K]^T ----------------
// ldc fixed at 128. Pass1 (!ACCUM): C = A@W^T + bias. Pass2 (ACCUM): C += A@W^T, then optional ReLU.

template <int K, int BN, bool ACCUM, bool RELU>
__global__ __launch_bounds__(256) void k_gemm(const float* __restrict__ A, int lda,
                                              const float* __restrict__ W,
                                              const float* __restrict__ bias,
                                              float* __restrict__ C) {
    constexpr int BM = 64, BK = 32;
    constexpr int TM = 4, TN = BN / 16;  // 8 (BN=128) or 4 (BN=64)
    __shared__ float As[BK][BM + 4];
    __shared__ float Ws[BK][BN + 4];
    const int tid = threadIdx.x;
    const int m0 = blockIdx.x * BM;
    const int tc = (tid & 15) * 4;   // column base (per 4-wide group)
    const int tr = (tid >> 4) * TM;  // row base

    float acc[TM][TN];
#pragma unroll
    for (int i = 0; i < TM; i++)
#pragma unroll
        for (int j = 0; j < TN; j++) acc[i][j] = 0.f;

    for (int kt = 0; kt < K; kt += BK) {
        // stage A tile (64 x 32), transposed to k-major
#pragma unroll
        for (int l = 0; l < 2; l++) {
            int idx = tid + l * 256;
            int row = idx >> 3;
            int kv = (idx & 7) * 4;
            float4 v = make_float4(0.f, 0.f, 0.f, 0.f);
            int grow = m0 + row;
            if (grow < NN) v = *(const float4*)(A + (size_t)grow * lda + kt + kv);
            As[kv + 0][row] = v.x;
            As[kv + 1][row] = v.y;
            As[kv + 2][row] = v.z;
            As[kv + 3][row] = v.w;
        }
        // stage W tile (BN x 32), transposed to k-major
#pragma unroll
        for (int l = 0; l < BN / 32; l++) {
            int idx = tid + l * 256;
            int row = idx >> 3;
            int kv = (idx & 7) * 4;
            float4 v = *(const float4*)(W + row * K + kt + kv);
            Ws[kv + 0][row] = v.x;
            Ws[kv + 1][row] = v.y;
            Ws[kv + 2][row] = v.z;
            Ws[kv + 3][row] = v.w;
        }
        __syncthreads();
#pragma unroll
        for (int k = 0; k < BK; k++) {
            float4 av = *(const float4*)&As[k][tr];
            float a[TM] = {av.x, av.y, av.z, av.w};
            float w[TN];
#pragma unroll
            for (int j0 = 0; j0 < TN; j0 += 4) {
                float4 wv = *(const float4*)&Ws[k][tc + (j0 >> 2) * 64];
                w[j0] = wv.x;
                w[j0 + 1] = wv.y;
                w[j0 + 2] = wv.z;
                w[j0 + 3] = wv.w;
            }
#pragma unroll
            for (int i = 0; i < TM; i++)
#pragma unroll
                for (int j = 0; j < TN; j++) acc[i][j] += a[i] * w[j];
        }
        __syncthreads();
    }
    // epilogue
#pragma unroll
    for (int i = 0; i < TM; i++) {
        int grow = m0 + tr + i;
        if (grow >= NN) continue;
#pragma unroll
        for (int j0 = 0; j0 < TN; j0 += 4) {
            int cb = tc + (j0 >> 2) * 64;
            float4 v = {acc[i][j0], acc[i][j0 + 1], acc[i][j0 + 2], acc[i][j0 + 3]};
            float* cp = C + (size_t)grow * 128 + cb;
            if (ACCUM) {
                float4 old = *(const float4*)cp;
                v.x += old.x; v.y += old.y; v.z += old.z; v.w += old.w;
            } else {
                v.x += bias[cb]; v.y += bias[cb + 1]; v.z += bias[cb + 2]; v.w += bias[cb + 3];
            }
            if (RELU) {
                v.x = fmaxf(v.x, 0.f); v.y = fmaxf(v.y, 0.f);
                v.z = fmaxf(v.z, 0.f); v.w = fmaxf(v.w, 0.f);
            }
            *(float4*)cp = v;
        }
    }
}

// ---------------- final decoder layer: out[N x 2] = h[N x 128(of ld128)] @ Wd2^T + bd2 ----------------

__global__ __launch_bounds__(256) void k_dec2(const float* __restrict__ h, const float* __restrict__ W,
                                              const float* __restrict__ b, float* __restrict__ out) {
    int node = blockIdx.x * 4 + (threadIdx.x >> 6);
    int lane = threadIdx.x & 63;
    float2 hv = *((const float2*)(h + (size_t)node * 128) + lane);
    float d0 = hv.x * W[2 * lane] + hv.y * W[2 * lane + 1];
    float d1 = hv.x * W[128 + 2 * lane] + hv.y * W[128 + 2 * lane + 1];
    for (int off = 32; off > 0; off >>= 1) {
        d0 += __shfl_down(d0, off);
        d1 += __shfl_down(d1, off);
    }
    if (lane == 0) {
        out[(size_t)node * 2 + 0] = d0 + b[0];
        out[(size_t)node * 2 + 1] = d1 + b[1];
    }
}

// ---------------- launch ----------------

extern "C" void kernel_launch(void* const* d_in, const int* in_sizes, int n_in,
                              void* d_out, int out_size, void* d_ws, size_t ws_size,
                              hipStream_t stream) {
    const float* x   = (const float*)d_in[0];
    const int*   ei  = (const int*)d_in[1];
    const float* Wl0 = (const float*)d_in[2];
    const float* bl0 = (const float*)d_in[3];
    const float* Wr0 = (const float*)d_in[4];
    const float* Wl1 = (const float*)d_in[5];
    const float* bl1 = (const float*)d_in[6];
    const float* Wr1 = (const float*)d_in[7];
    const float* Wl2 = (const float*)d_in[8];
    const float* bl2 = (const float*)d_in[9];
    const float* Wr2 = (const float*)d_in[10];
    const float* Wd1 = (const float*)d_in[11];
    const float* bd1 = (const float*)d_in[12];
    const float* Wd2 = (const float*)d_in[13];
    const float* bd2 = (const float*)d_in[14];
    float* out = (float*)d_out;

    char* ws = (char*)d_ws;
    size_t off = 0;
    auto alloc = [&](size_t bytes) {
        char* p = ws + off;
        off = (off + bytes + 255) & ~(size_t)255;
        return p;
    };
    int*   deg     = (int*)alloc((size_t)NN * 4);
    int*   row_ptr = (int*)alloc((size_t)(NN + 1) * 4);
    int*   cursor  = (int*)alloc((size_t)NN * 4);
    int*   bsum    = (int*)alloc(64 * 4);
    int*   col     = (int*)alloc((size_t)NE * 4);
    float* invd    = (float*)alloc((size_t)NN * 4);
    float* A       = (float*)alloc((size_t)NN * 128 * 4);
    float* B       = (float*)alloc((size_t)NN * 128 * 4);
    (void)ws_size;

    const int* srce = ei;
    const int* dste = ei + NE;

    // CSR build (per-launch; workspace is re-poisoned before every call)
    k_zero<<<(NN + 255) / 256, 256, 0, stream>>>(deg, NN);
    k_count<<<(NE + 255) / 256, 256, 0, stream>>>(dste, deg);
    const int nb = (NN + 2047) / 2048;  // 49
    k_scan_local<<<nb, 256, 0, stream>>>(deg, row_ptr, bsum, NN);
    k_scan_aux<<<1, 64, 0, stream>>>(bsum, nb);
    k_scan_finish<<<nb, 256, 0, stream>>>(row_ptr, bsum, cursor, deg, invd, NN);
    k_fill<<<(NE + 255) / 256, 256, 0, stream>>>(srce, dste, cursor, col);

    const int gGemm = (NN + 63) / 64;

    // Layer 0: in 64 -> out 128 (ReLU)
    k_aggregate<64, 64><<<NN / 4, 256, 0, stream>>>(x, row_ptr, col, invd, A);
    k_gemm<64, 128, false, false><<<gGemm, 256, 0, stream>>>(A, 128, Wl0, bl0, B);
    k_gemm<64, 128, true, true><<<gGemm, 256, 0, stream>>>(x, 64, Wr0, nullptr, B);

    // Layer 1: 128 -> 128 (ReLU)
    k_aggregate<128, 128><<<NN / 4, 256, 0, stream>>>(B, row_ptr, col, invd, A);
    k_gemm<128, 128, false, false><<<gGemm, 256, 0, stream>>>(A, 128, Wl1, bl1, A);
    k_gemm<128, 128, true, true><<<gGemm, 256, 0, stream>>>(B, 128, Wr1, nullptr, A);

    // Layer 2: 128 -> 64, no conv ReLU but decoder-entry ReLU fused here
    k_aggregate<128, 128><<<NN / 4, 256, 0, stream>>>(A, row_ptr, col, invd, B);
    k_gemm<128, 64, false, false><<<gGemm, 256, 0, stream>>>(B, 128, Wl2, bl2, B);
    k_gemm<128, 64, true, true><<<gGemm, 256, 0, stream>>>(A, 128, Wr2, nullptr, B);

    // Decoder: 64 -> 128 (ReLU) -> 2
    k_gemm<64, 128, false, true><<<gGemm, 256, 0, stream>>>(B, 128, Wd1, bd1, A);
    k_dec2<<<NN / 4, 256, 0, stream>>>(A, Wd2, bd2, out);
}

// Round 2
// 737.783 us; speedup vs baseline: 1.2392x; 1.2392x over previous
//
#include <hip/hip_runtime.h>
#include <cstdint>
#include <cstddef>

#define NN 100000
#define NE 1600000
#define BSH 9
#define NBUCK 196          // ceil(NN / 512)
#define P3_CHUNK 8192
#define P3_BLOCKS 196      // ceil(NE / P3_CHUNK)

// ---------------- CSR build via LDS-staged counting sort ----------------

__global__ __launch_bounds__(256) void k_zero_small(int* p, int n) {
    for (int i = threadIdx.x; i < n; i += 256) p[i] = 0;
}

// P1: global bucket histogram (bucket = dst >> 9)
__global__ __launch_bounds__(256) void k_hist(const int* __restrict__ dst, int* __restrict__ bcnt) {
    __shared__ int h[NBUCK];
    const int tid = threadIdx.x;
    if (tid < NBUCK) h[tid] = 0;
    __syncthreads();
    for (int e = blockIdx.x * 256 + tid; e < NE; e += gridDim.x * 256)
        atomicAdd(&h[dst[e] >> BSH], 1);
    __syncthreads();
    if (tid < NBUCK) atomicAdd(&bcnt[tid], h[tid]);
}

// P2: exclusive scan of bucket counts -> bstart, gcur
__global__ __launch_bounds__(256) void k_bscan(const int* __restrict__ bcnt, int* __restrict__ bstart,
                                               int* __restrict__ gcur) {
    __shared__ int sh[256];
    const int t = threadIdx.x;
    int v = (t < NBUCK) ? bcnt[t] : 0;
    sh[t] = v;
    __syncthreads();
    for (int off = 1; off < 256; off <<= 1) {
        int u = 0;
        if (t >= off) u = sh[t - off];
        __syncthreads();
        sh[t] += u;
        __syncthreads();
    }
    int excl = sh[t] - v;
    if (t < NBUCK) { bstart[t] = excl; gcur[t] = excl; }
    if (t == 0) bstart[NBUCK] = NE;
}

// P3: partition edges into bucket-grouped tmp[] with LDS reorder for coalesced writes.
// tmp element packs (src << 9) | (dst & 511).
__global__ __launch_bounds__(256) void k_partition(const int* __restrict__ srce, const int* __restrict__ dste,
                                                   int* __restrict__ gcur, int* __restrict__ tmp) {
    __shared__ int h[NBUCK], lstart[NBUCK], gbase[NBUCK], scn[256];
    __shared__ int s_pack[P3_CHUNK];
    __shared__ int s_gad[P3_CHUNK];
    const int tid = threadIdx.x;
    const int base = blockIdx.x * P3_CHUNK;
    if (tid < NBUCK) h[tid] = 0;
    __syncthreads();
    int rank[P3_CHUNK / 256];
#pragma unroll
    for (int i = 0; i < P3_CHUNK / 256; i++) {
        int idx = base + i * 256 + tid;
        if (idx < NE) rank[i] = atomicAdd(&h[dste[idx] >> BSH], 1);
    }
    __syncthreads();
    int hv = (tid < NBUCK) ? h[tid] : 0;
    if (tid < NBUCK) gbase[tid] = atomicAdd(&gcur[tid], hv);
    scn[tid] = hv;
    __syncthreads();
    for (int off = 1; off < 256; off <<= 1) {
        int u = 0;
        if (tid >= off) u = scn[tid - off];
        __syncthreads();
        scn[tid] += u;
        __syncthreads();
    }
    if (tid < NBUCK) lstart[tid] = scn[tid] - hv;
    __syncthreads();
#pragma unroll
    for (int i = 0; i < P3_CHUNK / 256; i++) {
        int idx = base + i * 256 + tid;
        if (idx < NE) {
            int d = dste[idx], s = srce[idx];
            int b = d >> BSH;
            int slot = lstart[b] + rank[i];
            s_pack[slot] = (s << BSH) | (d & ((1 << BSH) - 1));
            s_gad[slot] = gbase[b] + rank[i];
        }
    }
    __syncthreads();
    int chunkN = NE - base;
    if (chunkN > P3_CHUNK) chunkN = P3_CHUNK;
#pragma unroll
    for (int i = 0; i < P3_CHUNK / 256; i++) {
        int slot = i * 256 + tid;
        if (slot < chunkN) tmp[s_gad[slot]] = s_pack[slot];
    }
}

// P4: per-bucket counting sort (512 local nodes) -> row_ptr, inv_deg, col
__global__ __launch_bounds__(256) void k_bucket(const int* __restrict__ tmp, const int* __restrict__ bstart,
                                                int* __restrict__ row_ptr, int* __restrict__ col,
                                                float* __restrict__ invd) {
    __shared__ int cnt[512], cur[512], scn[256];
    const int b = blockIdx.x, tid = threadIdx.x;
    const int base = bstart[b];
    const int n = bstart[b + 1] - base;
    cnt[tid] = 0;
    cnt[tid + 256] = 0;
    __syncthreads();
    for (int k = tid; k < n; k += 256) atomicAdd(&cnt[tmp[base + k] & 511], 1);
    __syncthreads();
    int c0 = cnt[2 * tid], c1 = cnt[2 * tid + 1], s = c0 + c1;
    scn[tid] = s;
    __syncthreads();
    for (int off = 1; off < 256; off <<= 1) {
        int u = 0;
        if (tid >= off) u = scn[tid - off];
        __syncthreads();
        scn[tid] += u;
        __syncthreads();
    }
    int excl = scn[tid] - s;
    int node = (b << BSH) + 2 * tid;
    if (node < NN) {
        row_ptr[node] = base + excl;
        invd[node] = c0 ? 1.0f / (float)c0 : 0.0f;
    }
    if (node + 1 < NN) {
        row_ptr[node + 1] = base + excl + c0;
        invd[node + 1] = c1 ? 1.0f / (float)c1 : 0.0f;
    }
    cur[2 * tid] = base + excl;
    cur[2 * tid + 1] = base + excl + c0;
    if (b == 0 && tid == 0) row_ptr[NN] = NE;
    __syncthreads();
    for (int k = tid; k < n; k += 256) {
        int p = tmp[base + k];
        int pos = atomicAdd(&cur[p & 511], 1);
        col[pos] = p >> BSH;
    }
}

// ---------------- aggregation: one wave per destination node ----------------

template <int F, int LDI, int LDO>
__global__ __launch_bounds__(256) void k_agg(const float* __restrict__ h, const int* __restrict__ row_ptr,
                                             const int* __restrict__ col, const float* __restrict__ inv_deg,
                                             float* __restrict__ agg) {
    int node = blockIdx.x * 4 + (threadIdx.x >> 6);
    int lane = threadIdx.x & 63;
    int start = row_ptr[node], end = row_ptr[node + 1];
    if (F == 64) {
        float acc = 0.f;
        for (int cs = start; cs < end; cs += 64) {
            int n = end - cs;
            if (n > 64) n = 64;
            int my = (lane < n) ? col[cs + lane] : 0;
            for (int j = 0; j < n; j++) {
                int s = __shfl(my, j);
                acc += h[(size_t)s * LDI + lane];
            }
        }
        agg[(size_t)node * LDO + lane] = acc * inv_deg[node];
    } else {
        float accx = 0.f, accy = 0.f;
        for (int cs = start; cs < end; cs += 64) {
            int n = end - cs;
            if (n > 64) n = 64;
            int my = (lane < n) ? col[cs + lane] : 0;
            for (int j = 0; j < n; j++) {
                int s = __shfl(my, j);
                float2 v = *((const float2*)(h + (size_t)s * LDI) + lane);
                accx += v.x;
                accy += v.y;
            }
        }
        float w = inv_deg[node];
        float2 o;
        o.x = accx * w;
        o.y = accy * w;
        *((float2*)(agg + (size_t)node * LDO) + lane) = o;
    }
}

// fused layer-2 tail: out = relu(Q + invd * sum_{s in N(node)} P[s])   (all ld 64)
__global__ __launch_bounds__(256) void k_agg_relu64(const float* __restrict__ P, const float* __restrict__ Q,
                                                    const int* __restrict__ row_ptr, const int* __restrict__ col,
                                                    const float* __restrict__ inv_deg, float* __restrict__ out) {
    int node = blockIdx.x * 4 + (threadIdx.x >> 6);
    int lane = threadIdx.x & 63;
    int start = row_ptr[node], end = row_ptr[node + 1];
    float acc = 0.f;
    for (int cs = start; cs < end; cs += 64) {
        int n = end - cs;
        if (n > 64) n = 64;
        int my = (lane < n) ? col[cs + lane] : 0;
        for (int j = 0; j < n; j++) {
            int s = __shfl(my, j);
            acc += P[(size_t)s * 64 + lane];
        }
    }
    float v = Q[(size_t)node * 64 + lane] + inv_deg[node] * acc;
    out[(size_t)node * 64 + lane] = fmaxf(v, 0.f);
}

// ---------------- tiled fp32 GEMMs ----------------
// k_gemm1: C = A@W^T (+bias) (+relu).  BM=64, BK=32.

template <int K, int BN, bool BIAS, bool RELU>
__global__ __launch_bounds__(256) void k_gemm1(const float* __restrict__ A, int lda,
                                               const float* __restrict__ W, const float* __restrict__ bias,
                                               float* __restrict__ C, int ldc) {
    constexpr int BM = 64, BK = 32;
    constexpr int TM = 4, TN = BN / 16;
    __shared__ float As[BK][BM + 4];
    __shared__ float Ws[BK][BN + 4];
    const int tid = threadIdx.x;
    const int m0 = blockIdx.x * BM;
    const int tc = (tid & 15) * 4;
    const int tr = (tid >> 4) * TM;

    float acc[TM][TN];
#pragma unroll
    for (int i = 0; i < TM; i++)
#pragma unroll
        for (int j = 0; j < TN; j++) acc[i][j] = 0.f;

    for (int kt = 0; kt < K; kt += BK) {
#pragma unroll
        for (int l = 0; l < 2; l++) {
            int idx = tid + l * 256;
            int row = idx >> 3;
            int kv = (idx & 7) * 4;
            float4 v = make_float4(0.f, 0.f, 0.f, 0.f);
            int grow = m0 + row;
            if (grow < NN) v = *(const float4*)(A + (size_t)grow * lda + kt + kv);
            As[kv + 0][row] = v.x;
            As[kv + 1][row] = v.y;
            As[kv + 2][row] = v.z;
            As[kv + 3][row] = v.w;
        }
#pragma unroll
        for (int l = 0; l < BN / 32; l++) {
            int idx = tid + l * 256;
            int row = idx >> 3;
            int kv = (idx & 7) * 4;
            float4 v = *(const float4*)(W + row * K + kt + kv);
            Ws[kv + 0][row] = v.x;
            Ws[kv + 1][row] = v.y;
            Ws[kv + 2][row] = v.z;
            Ws[kv + 3][row] = v.w;
        }
        __syncthreads();
#pragma unroll
        for (int k = 0; k < BK; k++) {
            float4 av = *(const float4*)&As[k][tr];
            float a[TM] = {av.x, av.y, av.z, av.w};
            float w[TN];
#pragma unroll
            for (int j0 = 0; j0 < TN; j0 += 4) {
                float4 wv = *(const float4*)&Ws[k][tc + (j0 >> 2) * 64];
                w[j0] = wv.x; w[j0 + 1] = wv.y; w[j0 + 2] = wv.z; w[j0 + 3] = wv.w;
            }
#pragma unroll
            for (int i = 0; i < TM; i++)
#pragma unroll
                for (int j = 0; j < TN; j++) acc[i][j] += a[i] * w[j];
        }
        __syncthreads();
    }
#pragma unroll
    for (int i = 0; i < TM; i++) {
        int grow = m0 + tr + i;
        if (grow >= NN) continue;
#pragma unroll
        for (int j0 = 0; j0 < TN; j0 += 4) {
            int cb = tc + (j0 >> 2) * 64;
            float4 v = {acc[i][j0], acc[i][j0 + 1], acc[i][j0 + 2], acc[i][j0 + 3]};
            if (BIAS) {
                v.x += bias[cb]; v.y += bias[cb + 1]; v.z += bias[cb + 2]; v.w += bias[cb + 3];
            }
            if (RELU) {
                v.x = fmaxf(v.x, 0.f); v.y = fmaxf(v.y, 0.f);
                v.z = fmaxf(v.z, 0.f); v.w = fmaxf(v.w, 0.f);
            }
            *(float4*)(C + (size_t)grow * ldc + cb) = v;
        }
    }
}

// k_gemm2: C = A1@W1^T + A2@W2^T + bias (+relu). C may alias A1 or A2 rows
// (safe: each block's C rows are exactly its own A rows, fully read before epilogue).

template <int K1, int K2, int BN, bool RELU>
__global__ __launch_bounds__(256) void k_gemm2(const float* A1, int lda1, const float* __restrict__ W1,
                                               const float* A2, int lda2, const float* __restrict__ W2,
                                               const float* __restrict__ bias, float* C, int ldc) {
    constexpr int BM = 64, BK = 32;
    constexpr int TM = 4, TN = BN / 16;
    __shared__ float As[BK][BM + 4];
    __shared__ float Ws[BK][BN + 4];
    const int tid = threadIdx.x;
    const int m0 = blockIdx.x * BM;
    const int tc = (tid & 15) * 4;
    const int tr = (tid >> 4) * TM;

    float acc[TM][TN];
#pragma unroll
    for (int i = 0; i < TM; i++)
#pragma unroll
        for (int j = 0; j < TN; j++) acc[i][j] = 0.f;

    for (int ph = 0; ph < 2; ph++) {
        const float* A = ph ? A2 : A1;
        const int lda = ph ? lda2 : lda1;
        const float* W = ph ? W2 : W1;
        const int K = ph ? K2 : K1;
        for (int kt = 0; kt < K; kt += BK) {
#pragma unroll
            for (int l = 0; l < 2; l++) {
                int idx = tid + l * 256;
                int row = idx >> 3;
                int kv = (idx & 7) * 4;
                float4 v = make_float4(0.f, 0.f, 0.f, 0.f);
                int grow = m0 + row;
                if (grow < NN) v = *(const float4*)(A + (size_t)grow * lda + kt + kv);
                As[kv + 0][row] = v.x;
                As[kv + 1][row] = v.y;
                As[kv + 2][row] = v.z;
                As[kv + 3][row] = v.w;
            }
#pragma unroll
            for (int l = 0; l < BN / 32; l++) {
                int idx = tid + l * 256;
                int row = idx >> 3;
                int kv = (idx & 7) * 4;
                float4 v = *(const float4*)(W + row * K + kt + kv);
                Ws[kv + 0][row] = v.x;
                Ws[kv + 1][row] = v.y;
                Ws[kv + 2][row] = v.z;
                Ws[kv + 3][row] = v.w;
            }
            __syncthreads();
#pragma unroll
            for (int k = 0; k < BK; k++) {
                float4 av = *(const float4*)&As[k][tr];
                float a[TM] = {av.x, av.y, av.z, av.w};
                float w[TN];
#pragma unroll
                for (int j0 = 0; j0 < TN; j0 += 4) {
                    float4 wv = *(const float4*)&Ws[k][tc + (j0 >> 2) * 64];
                    w[j0] = wv.x; w[j0 + 1] = wv.y; w[j0 + 2] = wv.z; w[j0 + 3] = wv.w;
                }
#pragma unroll
                for (int i = 0; i < TM; i++)
#pragma unroll
                    for (int j = 0; j < TN; j++) acc[i][j] += a[i] * w[j];
            }
            __syncthreads();
        }
    }
#pragma unroll
    for (int i = 0; i < TM; i++) {
        int grow = m0 + tr + i;
        if (grow >= NN) continue;
#pragma unroll
        for (int j0 = 0; j0 < TN; j0 += 4) {
            int cb = tc + (j0 >> 2) * 64;
            float4 v = {acc[i][j0], acc[i][j0 + 1], acc[i][j0 + 2], acc[i][j0 + 3]};
            v.x += bias[cb]; v.y += bias[cb + 1]; v.z += bias[cb + 2]; v.w += bias[cb + 3];
            if (RELU) {
                v.x = fmaxf(v.x, 0.f); v.y = fmaxf(v.y, 0.f);
                v.z = fmaxf(v.z, 0.f); v.w = fmaxf(v.w, 0.f);
            }
            *(float4*)(C + (size_t)grow * ldc + cb) = v;
        }
    }
}

// ---------------- final decoder layer ----------------

__global__ __launch_bounds__(256) void k_dec2(const float* __restrict__ h, const float* __restrict__ W,
                                              const float* __restrict__ b, float* __restrict__ out) {
    int node = blockIdx.x * 4 + (threadIdx.x >> 6);
    int lane = threadIdx.x & 63;
    float2 hv = *((const float2*)(h + (size_t)node * 128) + lane);
    float d0 = hv.x * W[2 * lane] + hv.y * W[2 * lane + 1];
    float d1 = hv.x * W[128 + 2 * lane] + hv.y * W[128 + 2 * lane + 1];
    for (int off = 32; off > 0; off >>= 1) {
        d0 += __shfl_down(d0, off);
        d1 += __shfl_down(d1, off);
    }
    if (lane == 0) {
        out[(size_t)node * 2 + 0] = d0 + b[0];
        out[(size_t)node * 2 + 1] = d1 + b[1];
    }
}

// ---------------- launch ----------------

extern "C" void kernel_launch(void* const* d_in, const int* in_sizes, int n_in,
                              void* d_out, int out_size, void* d_ws, size_t ws_size,
                              hipStream_t stream) {
    const float* x   = (const float*)d_in[0];
    const int*   ei  = (const int*)d_in[1];
    const float* Wl0 = (const float*)d_in[2];
    const float* bl0 = (const float*)d_in[3];
    const float* Wr0 = (const float*)d_in[4];
    const float* Wl1 = (const float*)d_in[5];
    const float* bl1 = (const float*)d_in[6];
    const float* Wr1 = (const float*)d_in[7];
    const float* Wl2 = (const float*)d_in[8];
    const float* bl2 = (const float*)d_in[9];
    const float* Wr2 = (const float*)d_in[10];
    const float* Wd1 = (const float*)d_in[11];
    const float* bd1 = (const float*)d_in[12];
    const float* Wd2 = (const float*)d_in[13];
    const float* bd2 = (const float*)d_in[14];
    float* out = (float*)d_out;

    char* ws = (char*)d_ws;
    size_t off = 0;
    auto alloc = [&](size_t bytes) {
        char* p = ws + off;
        off = (off + bytes + 255) & ~(size_t)255;
        return p;
    };
    int*   bcnt    = (int*)alloc((size_t)NBUCK * 4);
    int*   bstart  = (int*)alloc((size_t)(NBUCK + 1) * 4);
    int*   gcur    = (int*)alloc((size_t)NBUCK * 4);
    int*   row_ptr = (int*)alloc((size_t)(NN + 1) * 4);
    float* invd    = (float*)alloc((size_t)NN * 4);
    int*   col     = (int*)alloc((size_t)NE * 4);
    float* G       = (float*)alloc((size_t)NN * 128 * 4);
    float* A       = (float*)alloc((size_t)NN * 128 * 4);
    int*   tmp     = (int*)A;  // alias: tmp dead before A's first use (L1 agg)
    (void)ws_size;

    const int* srce = ei;
    const int* dste = ei + NE;

    // CSR build (counting sort, no global scatter atomics on hot paths)
    k_zero_small<<<1, 256, 0, stream>>>(bcnt, NBUCK);
    k_hist<<<400, 256, 0, stream>>>(dste, bcnt);
    k_bscan<<<1, 256, 0, stream>>>(bcnt, bstart, gcur);
    k_partition<<<P3_BLOCKS, 256, 0, stream>>>(srce, dste, gcur, tmp);
    k_bucket<<<NBUCK, 256, 0, stream>>>(tmp, bstart, row_ptr, col, invd);

    const int gGemm = (NN + 63) / 64;  // 1563
    const int gNode = NN / 4;          // 25000

    // Layer 0: 64 -> 128, ReLU.  agg(x) -> G(ld128, cols 0..63); fused GEMM in-place into G.
    k_agg<64, 64, 128><<<gNode, 256, 0, stream>>>(x, row_ptr, col, invd, G);
    k_gemm2<64, 64, 128, true><<<gGemm, 256, 0, stream>>>(G, 128, Wl0, x, 64, Wr0, bl0, G, 128);

    // Layer 1: 128 -> 128, ReLU.  agg(G) -> A; fused GEMM in-place into A.
    k_agg<128, 128, 128><<<gNode, 256, 0, stream>>>(G, row_ptr, col, invd, A);
    k_gemm2<128, 128, 128, true><<<gGemm, 256, 0, stream>>>(A, 128, Wl1, G, 128, Wr1, bl1, A, 128);

    // Layer 2 (transform-before-aggregate): P = A@Wl2^T, Q = A@Wr2^T + b2;
    // h2 = relu(Q + mean-agg(P))  -> A (ld64). Decoder-entry ReLU fused.
    k_gemm1<128, 64, false, false><<<gGemm, 256, 0, stream>>>(A, 128, Wl2, nullptr, G, 64);
    k_gemm1<128, 64, true, false><<<gGemm, 256, 0, stream>>>(A, 128, Wr2, bl2, G + (size_t)NN * 64, 64);
    k_agg_relu64<<<gNode, 256, 0, stream>>>(G, G + (size_t)NN * 64, row_ptr, col, invd, A);

    // Decoder: 64 -> 128 (ReLU) -> 2
    k_gemm1<64, 128, true, true><<<gGemm, 256, 0, stream>>>(A, 64, Wd1, bd1, G, 128);
    k_dec2<<<gNode, 256, 0, stream>>>(G, Wd2, bd2, out);
}

// Round 3
// 636.303 us; speedup vs baseline: 1.4368x; 1.1595x over previous
//
#include <hip/hip_runtime.h>
#include <cstdint>
#include <cstddef>

#define NN 100000
#define NE 1600000
#define BSH 9
#define NBUCK 196          // ceil(NN / 512)
#define P3_CHUNK 8192
#define P3_BLOCKS 196      // ceil(NE / P3_CHUNK)

// ---------------- CSR build via LDS-staged counting sort ----------------

__global__ __launch_bounds__(256) void k_zero_small(int* p, int n) {
    for (int i = threadIdx.x; i < n; i += 256) p[i] = 0;
}

// P1: global bucket histogram (bucket = dst >> 9)
__global__ __launch_bounds__(256) void k_hist(const int* __restrict__ dst, int* __restrict__ bcnt) {
    __shared__ int h[NBUCK];
    const int tid = threadIdx.x;
    if (tid < NBUCK) h[tid] = 0;
    __syncthreads();
    for (int e = blockIdx.x * 256 + tid; e < NE; e += gridDim.x * 256)
        atomicAdd(&h[dst[e] >> BSH], 1);
    __syncthreads();
    if (tid < NBUCK) atomicAdd(&bcnt[tid], h[tid]);
}

// P2: exclusive scan of bucket counts -> bstart, gcur
__global__ __launch_bounds__(256) void k_bscan(const int* __restrict__ bcnt, int* __restrict__ bstart,
                                               int* __restrict__ gcur) {
    __shared__ int sh[256];
    const int t = threadIdx.x;
    int v = (t < NBUCK) ? bcnt[t] : 0;
    sh[t] = v;
    __syncthreads();
    for (int off = 1; off < 256; off <<= 1) {
        int u = 0;
        if (t >= off) u = sh[t - off];
        __syncthreads();
        sh[t] += u;
        __syncthreads();
    }
    int excl = sh[t] - v;
    if (t < NBUCK) { bstart[t] = excl; gcur[t] = excl; }
    if (t == 0) bstart[NBUCK] = NE;
}

// P3: partition edges into bucket-grouped tmp[] with LDS reorder for coalesced writes.
// tmp element packs (src << 9) | (dst & 511).
__global__ __launch_bounds__(256) void k_partition(const int* __restrict__ srce, const int* __restrict__ dste,
                                                   int* __restrict__ gcur, int* __restrict__ tmp) {
    __shared__ int h[NBUCK], lstart[NBUCK], gbase[NBUCK], scn[256];
    __shared__ int s_pack[P3_CHUNK];
    __shared__ int s_gad[P3_CHUNK];
    const int tid = threadIdx.x;
    const int base = blockIdx.x * P3_CHUNK;
    if (tid < NBUCK) h[tid] = 0;
    __syncthreads();
    int rank[P3_CHUNK / 256];
#pragma unroll
    for (int i = 0; i < P3_CHUNK / 256; i++) {
        int idx = base + i * 256 + tid;
        if (idx < NE) rank[i] = atomicAdd(&h[dste[idx] >> BSH], 1);
    }
    __syncthreads();
    int hv = (tid < NBUCK) ? h[tid] : 0;
    if (tid < NBUCK) gbase[tid] = atomicAdd(&gcur[tid], hv);
    scn[tid] = hv;
    __syncthreads();
    for (int off = 1; off < 256; off <<= 1) {
        int u = 0;
        if (tid >= off) u = scn[tid - off];
        __syncthreads();
        scn[tid] += u;
        __syncthreads();
    }
    if (tid < NBUCK) lstart[tid] = scn[tid] - hv;
    __syncthreads();
#pragma unroll
    for (int i = 0; i < P3_CHUNK / 256; i++) {
        int idx = base + i * 256 + tid;
        if (idx < NE) {
            int d = dste[idx], s = srce[idx];
            int b = d >> BSH;
            int slot = lstart[b] + rank[i];
            s_pack[slot] = (s << BSH) | (d & ((1 << BSH) - 1));
            s_gad[slot] = gbase[b] + rank[i];
        }
    }
    __syncthreads();
    int chunkN = NE - base;
    if (chunkN > P3_CHUNK) chunkN = P3_CHUNK;
#pragma unroll
    for (int i = 0; i < P3_CHUNK / 256; i++) {
        int slot = i * 256 + tid;
        if (slot < chunkN) tmp[s_gad[slot]] = s_pack[slot];
    }
}

// P4: per-bucket counting sort (512 local nodes) -> row_ptr, inv_deg, col
__global__ __launch_bounds__(256) void k_bucket(const int* __restrict__ tmp, const int* __restrict__ bstart,
                                                int* __restrict__ row_ptr, int* __restrict__ col,
                                                float* __restrict__ invd) {
    __shared__ int cnt[512], cur[512], scn[256];
    const int b = blockIdx.x, tid = threadIdx.x;
    const int base = bstart[b];
    const int n = bstart[b + 1] - base;
    cnt[tid] = 0;
    cnt[tid + 256] = 0;
    __syncthreads();
    for (int k = tid; k < n; k += 256) atomicAdd(&cnt[tmp[base + k] & 511], 1);
    __syncthreads();
    int c0 = cnt[2 * tid], c1 = cnt[2 * tid + 1], s = c0 + c1;
    scn[tid] = s;
    __syncthreads();
    for (int off = 1; off < 256; off <<= 1) {
        int u = 0;
        if (tid >= off) u = scn[tid - off];
        __syncthreads();
        scn[tid] += u;
        __syncthreads();
    }
    int excl = scn[tid] - s;
    int node = (b << BSH) + 2 * tid;
    if (node < NN) {
        row_ptr[node] = base + excl;
        invd[node] = c0 ? 1.0f / (float)c0 : 0.0f;
    }
    if (node + 1 < NN) {
        row_ptr[node + 1] = base + excl + c0;
        invd[node + 1] = c1 ? 1.0f / (float)c1 : 0.0f;
    }
    cur[2 * tid] = base + excl;
    cur[2 * tid + 1] = base + excl + c0;
    if (b == 0 && tid == 0) row_ptr[NN] = NE;
    __syncthreads();
    for (int k = tid; k < n; k += 256) {
        int p = tmp[base + k];
        int pos = atomicAdd(&cur[p & 511], 1);
        col[pos] = p >> BSH;
    }
}

// ---------------- aggregation: one wave per destination node ----------------
// 8-deep unrolled gather: 8 independent loads in flight per wave (MLP), 8 accumulators.

template <int F, int LDI, int LDO>
__global__ __launch_bounds__(256) void k_agg(const float* __restrict__ h, const int* __restrict__ row_ptr,
                                             const int* __restrict__ col, const float* __restrict__ inv_deg,
                                             float* __restrict__ agg) {
    int node = blockIdx.x * 4 + (threadIdx.x >> 6);
    int lane = threadIdx.x & 63;
    int start = row_ptr[node], end = row_ptr[node + 1];
    if (F == 64) {
        float a0 = 0.f, a1 = 0.f, a2 = 0.f, a3 = 0.f, a4 = 0.f, a5 = 0.f, a6 = 0.f, a7 = 0.f;
        for (int cs = start; cs < end; cs += 64) {
            int n = end - cs;
            if (n > 64) n = 64;
            int my = (lane < n) ? col[cs + lane] : 0;
            int j = 0;
            for (; j + 8 <= n; j += 8) {
                int s0 = __shfl(my, j + 0), s1 = __shfl(my, j + 1);
                int s2 = __shfl(my, j + 2), s3 = __shfl(my, j + 3);
                int s4 = __shfl(my, j + 4), s5 = __shfl(my, j + 5);
                int s6 = __shfl(my, j + 6), s7 = __shfl(my, j + 7);
                float v0 = h[(size_t)s0 * LDI + lane];
                float v1 = h[(size_t)s1 * LDI + lane];
                float v2 = h[(size_t)s2 * LDI + lane];
                float v3 = h[(size_t)s3 * LDI + lane];
                float v4 = h[(size_t)s4 * LDI + lane];
                float v5 = h[(size_t)s5 * LDI + lane];
                float v6 = h[(size_t)s6 * LDI + lane];
                float v7 = h[(size_t)s7 * LDI + lane];
                a0 += v0; a1 += v1; a2 += v2; a3 += v3;
                a4 += v4; a5 += v5; a6 += v6; a7 += v7;
            }
            for (; j < n; j++) {
                int s = __shfl(my, j);
                a0 += h[(size_t)s * LDI + lane];
            }
        }
        float acc = ((a0 + a1) + (a2 + a3)) + ((a4 + a5) + (a6 + a7));
        agg[(size_t)node * LDO + lane] = acc * inv_deg[node];
    } else {
        const float2* hp = (const float2*)h;
        const int ld2 = LDI / 2;
        float2 a0 = {0.f, 0.f}, a1 = {0.f, 0.f}, a2 = {0.f, 0.f}, a3 = {0.f, 0.f};
        float2 a4 = {0.f, 0.f}, a5 = {0.f, 0.f}, a6 = {0.f, 0.f}, a7 = {0.f, 0.f};
        for (int cs = start; cs < end; cs += 64) {
            int n = end - cs;
            if (n > 64) n = 64;
            int my = (lane < n) ? col[cs + lane] : 0;
            int j = 0;
            for (; j + 8 <= n; j += 8) {
                int s0 = __shfl(my, j + 0), s1 = __shfl(my, j + 1);
                int s2 = __shfl(my, j + 2), s3 = __shfl(my, j + 3);
                int s4 = __shfl(my, j + 4), s5 = __shfl(my, j + 5);
                int s6 = __shfl(my, j + 6), s7 = __shfl(my, j + 7);
                float2 v0 = hp[(size_t)s0 * ld2 + lane];
                float2 v1 = hp[(size_t)s1 * ld2 + lane];
                float2 v2 = hp[(size_t)s2 * ld2 + lane];
                float2 v3 = hp[(size_t)s3 * ld2 + lane];
                float2 v4 = hp[(size_t)s4 * ld2 + lane];
                float2 v5 = hp[(size_t)s5 * ld2 + lane];
                float2 v6 = hp[(size_t)s6 * ld2 + lane];
                float2 v7 = hp[(size_t)s7 * ld2 + lane];
                a0.x += v0.x; a0.y += v0.y; a1.x += v1.x; a1.y += v1.y;
                a2.x += v2.x; a2.y += v2.y; a3.x += v3.x; a3.y += v3.y;
                a4.x += v4.x; a4.y += v4.y; a5.x += v5.x; a5.y += v5.y;
                a6.x += v6.x; a6.y += v6.y; a7.x += v7.x; a7.y += v7.y;
            }
            for (; j < n; j++) {
                int s = __shfl(my, j);
                float2 v = hp[(size_t)s * ld2 + lane];
                a0.x += v.x;
                a0.y += v.y;
            }
        }
        float w = inv_deg[node];
        float2 o;
        o.x = (((a0.x + a1.x) + (a2.x + a3.x)) + ((a4.x + a5.x) + (a6.x + a7.x))) * w;
        o.y = (((a0.y + a1.y) + (a2.y + a3.y)) + ((a4.y + a5.y) + (a6.y + a7.y))) * w;
        *((float2*)(agg + (size_t)node * LDO) + lane) = o;
    }
}

// fused layer-2 tail: out = relu(Q + invd * sum_{s in N(node)} P[s])   (all ld 64)
__global__ __launch_bounds__(256) void k_agg_relu64(const float* __restrict__ P, const float* __restrict__ Q,
                                                    const int* __restrict__ row_ptr, const int* __restrict__ col,
                                                    const float* __restrict__ inv_deg, float* __restrict__ out) {
    int node = blockIdx.x * 4 + (threadIdx.x >> 6);
    int lane = threadIdx.x & 63;
    int start = row_ptr[node], end = row_ptr[node + 1];
    float a0 = 0.f, a1 = 0.f, a2 = 0.f, a3 = 0.f, a4 = 0.f, a5 = 0.f, a6 = 0.f, a7 = 0.f;
    for (int cs = start; cs < end; cs += 64) {
        int n = end - cs;
        if (n > 64) n = 64;
        int my = (lane < n) ? col[cs + lane] : 0;
        int j = 0;
        for (; j + 8 <= n; j += 8) {
            int s0 = __shfl(my, j + 0), s1 = __shfl(my, j + 1);
            int s2 = __shfl(my, j + 2), s3 = __shfl(my, j + 3);
            int s4 = __shfl(my, j + 4), s5 = __shfl(my, j + 5);
            int s6 = __shfl(my, j + 6), s7 = __shfl(my, j + 7);
            float v0 = P[(size_t)s0 * 64 + lane];
            float v1 = P[(size_t)s1 * 64 + lane];
            float v2 = P[(size_t)s2 * 64 + lane];
            float v3 = P[(size_t)s3 * 64 + lane];
            float v4 = P[(size_t)s4 * 64 + lane];
            float v5 = P[(size_t)s5 * 64 + lane];
            float v6 = P[(size_t)s6 * 64 + lane];
            float v7 = P[(size_t)s7 * 64 + lane];
            a0 += v0; a1 += v1; a2 += v2; a3 += v3;
            a4 += v4; a5 += v5; a6 += v6; a7 += v7;
        }
        for (; j < n; j++) {
            int s = __shfl(my, j);
            a0 += P[(size_t)s * 64 + lane];
        }
    }
    float acc = ((a0 + a1) + (a2 + a3)) + ((a4 + a5) + (a6 + a7));
    float v = Q[(size_t)node * 64 + lane] + inv_deg[node] * acc;
    out[(size_t)node * 64 + lane] = fmaxf(v, 0.f);
}

// ---------------- tiled fp32 GEMMs ----------------
// k_gemm1: C = A@W^T (+bias) (+relu).  BM=64, BK=32.

template <int K, int BN, bool BIAS, bool RELU>
__global__ __launch_bounds__(256) void k_gemm1(const float* __restrict__ A, int lda,
                                               const float* __restrict__ W, const float* __restrict__ bias,
                                               float* __restrict__ C, int ldc) {
    constexpr int BM = 64, BK = 32;
    constexpr int TM = 4, TN = BN / 16;
    __shared__ float As[BK][BM + 4];
    __shared__ float Ws[BK][BN + 4];
    const int tid = threadIdx.x;
    const int m0 = blockIdx.x * BM;
    const int tc = (tid & 15) * 4;
    const int tr = (tid >> 4) * TM;

    float acc[TM][TN];
#pragma unroll
    for (int i = 0; i < TM; i++)
#pragma unroll
        for (int j = 0; j < TN; j++) acc[i][j] = 0.f;

    for (int kt = 0; kt < K; kt += BK) {
#pragma unroll
        for (int l = 0; l < 2; l++) {
            int idx = tid + l * 256;
            int row = idx >> 3;
            int kv = (idx & 7) * 4;
            float4 v = make_float4(0.f, 0.f, 0.f, 0.f);
            int grow = m0 + row;
            if (grow < NN) v = *(const float4*)(A + (size_t)grow * lda + kt + kv);
            As[kv + 0][row] = v.x;
            As[kv + 1][row] = v.y;
            As[kv + 2][row] = v.z;
            As[kv + 3][row] = v.w;
        }
#pragma unroll
        for (int l = 0; l < BN / 32; l++) {
            int idx = tid + l * 256;
            int row = idx >> 3;
            int kv = (idx & 7) * 4;
            float4 v = *(const float4*)(W + row * K + kt + kv);
            Ws[kv + 0][row] = v.x;
            Ws[kv + 1][row] = v.y;
            Ws[kv + 2][row] = v.z;
            Ws[kv + 3][row] = v.w;
        }
        __syncthreads();
#pragma unroll
        for (int k = 0; k < BK; k++) {
            float4 av = *(const float4*)&As[k][tr];
            float a[TM] = {av.x, av.y, av.z, av.w};
            float w[TN];
#pragma unroll
            for (int j0 = 0; j0 < TN; j0 += 4) {
                float4 wv = *(const float4*)&Ws[k][tc + (j0 >> 2) * 64];
                w[j0] = wv.x; w[j0 + 1] = wv.y; w[j0 + 2] = wv.z; w[j0 + 3] = wv.w;
            }
#pragma unroll
            for (int i = 0; i < TM; i++)
#pragma unroll
                for (int j = 0; j < TN; j++) acc[i][j] += a[i] * w[j];
        }
        __syncthreads();
    }
#pragma unroll
    for (int i = 0; i < TM; i++) {
        int grow = m0 + tr + i;
        if (grow >= NN) continue;
#pragma unroll
        for (int j0 = 0; j0 < TN; j0 += 4) {
            int cb = tc + (j0 >> 2) * 64;
            float4 v = {acc[i][j0], acc[i][j0 + 1], acc[i][j0 + 2], acc[i][j0 + 3]};
            if (BIAS) {
                v.x += bias[cb]; v.y += bias[cb + 1]; v.z += bias[cb + 2]; v.w += bias[cb + 3];
            }
            if (RELU) {
                v.x = fmaxf(v.x, 0.f); v.y = fmaxf(v.y, 0.f);
                v.z = fmaxf(v.z, 0.f); v.w = fmaxf(v.w, 0.f);
            }
            *(float4*)(C + (size_t)grow * ldc + cb) = v;
        }
    }
}

// k_gemm2: C = A1@W1^T + A2@W2^T + bias (+relu). C may alias A1 or A2 rows
// (safe: each block's C rows are exactly its own A rows, fully read before epilogue).

template <int K1, int K2, int BN, bool RELU>
__global__ __launch_bounds__(256) void k_gemm2(const float* A1, int lda1, const float* __restrict__ W1,
                                               const float* A2, int lda2, const float* __restrict__ W2,
                                               const float* __restrict__ bias, float* C, int ldc) {
    constexpr int BM = 64, BK = 32;
    constexpr int TM = 4, TN = BN / 16;
    __shared__ float As[BK][BM + 4];
    __shared__ float Ws[BK][BN + 4];
    const int tid = threadIdx.x;
    const int m0 = blockIdx.x * BM;
    const int tc = (tid & 15) * 4;
    const int tr = (tid >> 4) * TM;

    float acc[TM][TN];
#pragma unroll
    for (int i = 0; i < TM; i++)
#pragma unroll
        for (int j = 0; j < TN; j++) acc[i][j] = 0.f;

    for (int ph = 0; ph < 2; ph++) {
        const float* A = ph ? A2 : A1;
        const int lda = ph ? lda2 : lda1;
        const float* W = ph ? W2 : W1;
        const int K = ph ? K2 : K1;
        for (int kt = 0; kt < K; kt += BK) {
#pragma unroll
            for (int l = 0; l < 2; l++) {
                int idx = tid + l * 256;
                int row = idx >> 3;
                int kv = (idx & 7) * 4;
                float4 v = make_float4(0.f, 0.f, 0.f, 0.f);
                int grow = m0 + row;
                if (grow < NN) v = *(const float4*)(A + (size_t)grow * lda + kt + kv);
                As[kv + 0][row] = v.x;
                As[kv + 1][row] = v.y;
                As[kv + 2][row] = v.z;
                As[kv + 3][row] = v.w;
            }
#pragma unroll
            for (int l = 0; l < BN / 32; l++) {
                int idx = tid + l * 256;
                int row = idx >> 3;
                int kv = (idx & 7) * 4;
                float4 v = *(const float4*)(W + row * K + kt + kv);
                Ws[kv + 0][row] = v.x;
                Ws[kv + 1][row] = v.y;
                Ws[kv + 2][row] = v.z;
                Ws[kv + 3][row] = v.w;
            }
            __syncthreads();
#pragma unroll
            for (int k = 0; k < BK; k++) {
                float4 av = *(const float4*)&As[k][tr];
                float a[TM] = {av.x, av.y, av.z, av.w};
                float w[TN];
#pragma unroll
                for (int j0 = 0; j0 < TN; j0 += 4) {
                    float4 wv = *(const float4*)&Ws[k][tc + (j0 >> 2) * 64];
                    w[j0] = wv.x; w[j0 + 1] = wv.y; w[j0 + 2] = wv.z; w[j0 + 3] = wv.w;
                }
#pragma unroll
                for (int i = 0; i < TM; i++)
#pragma unroll
                    for (int j = 0; j < TN; j++) acc[i][j] += a[i] * w[j];
            }
            __syncthreads();
        }
    }
#pragma unroll
    for (int i = 0; i < TM; i++) {
        int grow = m0 + tr + i;
        if (grow >= NN) continue;
#pragma unroll
        for (int j0 = 0; j0 < TN; j0 += 4) {
            int cb = tc + (j0 >> 2) * 64;
            float4 v = {acc[i][j0], acc[i][j0 + 1], acc[i][j0 + 2], acc[i][j0 + 3]};
            v.x += bias[cb]; v.y += bias[cb + 1]; v.z += bias[cb + 2]; v.w += bias[cb + 3];
            if (RELU) {
                v.x = fmaxf(v.x, 0.f); v.y = fmaxf(v.y, 0.f);
                v.z = fmaxf(v.z, 0.f); v.w = fmaxf(v.w, 0.f);
            }
            *(float4*)(C + (size_t)grow * ldc + cb) = v;
        }
    }
}

// ---------------- final decoder layer ----------------

__global__ __launch_bounds__(256) void k_dec2(const float* __restrict__ h, const float* __restrict__ W,
                                              const float* __restrict__ b, float* __restrict__ out) {
    int node = blockIdx.x * 4 + (threadIdx.x >> 6);
    int lane = threadIdx.x & 63;
    float2 hv = *((const float2*)(h + (size_t)node * 128) + lane);
    float d0 = hv.x * W[2 * lane] + hv.y * W[2 * lane + 1];
    float d1 = hv.x * W[128 + 2 * lane] + hv.y * W[128 + 2 * lane + 1];
    for (int off = 32; off > 0; off >>= 1) {
        d0 += __shfl_down(d0, off);
        d1 += __shfl_down(d1, off);
    }
    if (lane == 0) {
        out[(size_t)node * 2 + 0] = d0 + b[0];
        out[(size_t)node * 2 + 1] = d1 + b[1];
    }
}

// ---------------- launch ----------------

extern "C" void kernel_launch(void* const* d_in, const int* in_sizes, int n_in,
                              void* d_out, int out_size, void* d_ws, size_t ws_size,
                              hipStream_t stream) {
    const float* x   = (const float*)d_in[0];
    const int*   ei  = (const int*)d_in[1];
    const float* Wl0 = (const float*)d_in[2];
    const float* bl0 = (const float*)d_in[3];
    const float* Wr0 = (const float*)d_in[4];
    const float* Wl1 = (const float*)d_in[5];
    const float* bl1 = (const float*)d_in[6];
    const float* Wr1 = (const float*)d_in[7];
    const float* Wl2 = (const float*)d_in[8];
    const float* bl2 = (const float*)d_in[9];
    const float* Wr2 = (const float*)d_in[10];
    const float* Wd1 = (const float*)d_in[11];
    const float* bd1 = (const float*)d_in[12];
    const float* Wd2 = (const float*)d_in[13];
    const float* bd2 = (const float*)d_in[14];
    float* out = (float*)d_out;

    char* ws = (char*)d_ws;
    size_t off = 0;
    auto alloc = [&](size_t bytes) {
        char* p = ws + off;
        off = (off + bytes + 255) & ~(size_t)255;
        return p;
    };
    int*   bcnt    = (int*)alloc((size_t)NBUCK * 4);
    int*   bstart  = (int*)alloc((size_t)(NBUCK + 1) * 4);
    int*   gcur    = (int*)alloc((size_t)NBUCK * 4);
    int*   row_ptr = (int*)alloc((size_t)(NN + 1) * 4);
    float* invd    = (float*)alloc((size_t)NN * 4);
    int*   col     = (int*)alloc((size_t)NE * 4);
    float* G       = (float*)alloc((size_t)NN * 128 * 4);
    float* A       = (float*)alloc((size_t)NN * 128 * 4);
    int*   tmp     = (int*)A;  // alias: tmp dead before A's first use (L1 agg)
    (void)ws_size;

    const int* srce = ei;
    const int* dste = ei + NE;

    // CSR build (counting sort, no global scatter atomics on hot paths)
    k_zero_small<<<1, 256, 0, stream>>>(bcnt, NBUCK);
    k_hist<<<400, 256, 0, stream>>>(dste, bcnt);
    k_bscan<<<1, 256, 0, stream>>>(bcnt, bstart, gcur);
    k_partition<<<P3_BLOCKS, 256, 0, stream>>>(srce, dste, gcur, tmp);
    k_bucket<<<NBUCK, 256, 0, stream>>>(tmp, bstart, row_ptr, col, invd);

    const int gGemm = (NN + 63) / 64;  // 1563
    const int gNode = NN / 4;          // 25000

    // Layer 0: 64 -> 128, ReLU.  agg(x) -> G(ld128, cols 0..63); fused GEMM in-place into G.
    k_agg<64, 64, 128><<<gNode, 256, 0, stream>>>(x, row_ptr, col, invd, G);
    k_gemm2<64, 64, 128, true><<<gGemm, 256, 0, stream>>>(G, 128, Wl0, x, 64, Wr0, bl0, G, 128);

    // Layer 1: 128 -> 128, ReLU.  agg(G) -> A; fused GEMM in-place into A.
    k_agg<128, 128, 128><<<gNode, 256, 0, stream>>>(G, row_ptr, col, invd, A);
    k_gemm2<128, 128, 128, true><<<gGemm, 256, 0, stream>>>(A, 128, Wl1, G, 128, Wr1, bl1, A, 128);

    // Layer 2 (transform-before-aggregate): P = A@Wl2^T, Q = A@Wr2^T + b2;
    // h2 = relu(Q + mean-agg(P))  -> A (ld64). Decoder-entry ReLU fused.
    k_gemm1<128, 64, false, false><<<gGemm, 256, 0, stream>>>(A, 128, Wl2, nullptr, G, 64);
    k_gemm1<128, 64, true, false><<<gGemm, 256, 0, stream>>>(A, 128, Wr2, bl2, G + (size_t)NN * 64, 64);
    k_agg_relu64<<<gNode, 256, 0, stream>>>(G, G + (size_t)NN * 64, row_ptr, col, invd, A);

    // Decoder: 64 -> 128 (ReLU) -> 2
    k_gemm1<64, 128, true, true><<<gGemm, 256, 0, stream>>>(A, 64, Wd1, bd1, G, 128);
    k_dec2<<<gNode, 256, 0, stream>>>(G, Wd2, bd2, out);
}

// Round 4
// 548.332 us; speedup vs baseline: 1.6673x; 1.1604x over previous
//
#include <hip/hip_runtime.h>
#include <cstdint>
#include <cstddef>

#define NN 100000
#define NE 1600000
#define BSH 9
#define NBUCK 196          // ceil(NN / 512)
#define P3_CHUNK 8192
#define P3_BLOCKS 196      // ceil(NE / P3_CHUNK)

typedef __attribute__((ext_vector_type(8))) short short8;
typedef __attribute__((ext_vector_type(4))) float f32x4;

// ---------------- split-bf16 helpers ----------------
// packed uint: bits[15:0] = hi bf16, bits[31:16] = lo bf16, v ~= hi + lo

__device__ inline unsigned pack_split(float v) {
    unsigned u = __builtin_bit_cast(unsigned, v);
    unsigned hi = (u + 0x7fffu + ((u >> 16) & 1u)) >> 16;   // RN-even bf16
    float vh = __builtin_bit_cast(float, hi << 16);
    float r = v - vh;                                        // exact
    unsigned u2 = __builtin_bit_cast(unsigned, r);
    unsigned lo = (u2 + 0x7fffu + ((u2 >> 16) & 1u)) >> 16;  // RN-even bf16
    return hi | (lo << 16);
}

__device__ inline float rec_sum(unsigned u) {  // reconstruct fp32 ~= hi + lo
    return __builtin_bit_cast(float, u << 16) + __builtin_bit_cast(float, u & 0xffff0000u);
}

// extract 8 (hi,lo) bf16 frag pairs from 8 packed uints (32B) in LDS
__device__ inline void frag_extract(const unsigned* p, short8& hi, short8& lo) {
    uint4 p0 = *(const uint4*)p;
    uint4 p1 = *(const uint4*)(p + 4);
    unsigned h0 = __builtin_amdgcn_perm(p0.y, p0.x, 0x05040100u);
    unsigned l0 = __builtin_amdgcn_perm(p0.y, p0.x, 0x07060302u);
    unsigned h1 = __builtin_amdgcn_perm(p0.w, p0.z, 0x05040100u);
    unsigned l1 = __builtin_amdgcn_perm(p0.w, p0.z, 0x07060302u);
    unsigned h2 = __builtin_amdgcn_perm(p1.y, p1.x, 0x05040100u);
    unsigned l2 = __builtin_amdgcn_perm(p1.y, p1.x, 0x07060302u);
    unsigned h3 = __builtin_amdgcn_perm(p1.w, p1.z, 0x05040100u);
    unsigned l3 = __builtin_amdgcn_perm(p1.w, p1.z, 0x07060302u);
    uint4 H = {h0, h1, h2, h3};
    uint4 L = {l0, l1, l2, l3};
    hi = __builtin_bit_cast(short8, H);
    lo = __builtin_bit_cast(short8, L);
}

// ---------------- CSR build via LDS-staged counting sort ----------------

__global__ __launch_bounds__(256) void k_zero_small(int* p, int n) {
    for (int i = threadIdx.x; i < n; i += 256) p[i] = 0;
}

__global__ __launch_bounds__(256) void k_hist(const int* __restrict__ dst, int* __restrict__ bcnt) {
    __shared__ int h[NBUCK];
    const int tid = threadIdx.x;
    if (tid < NBUCK) h[tid] = 0;
    __syncthreads();
    for (int e = blockIdx.x * 256 + tid; e < NE; e += gridDim.x * 256)
        atomicAdd(&h[dst[e] >> BSH], 1);
    __syncthreads();
    if (tid < NBUCK) atomicAdd(&bcnt[tid], h[tid]);
}

__global__ __launch_bounds__(256) void k_bscan(const int* __restrict__ bcnt, int* __restrict__ bstart,
                                               int* __restrict__ gcur) {
    __shared__ int sh[256];
    const int t = threadIdx.x;
    int v = (t < NBUCK) ? bcnt[t] : 0;
    sh[t] = v;
    __syncthreads();
    for (int off = 1; off < 256; off <<= 1) {
        int u = 0;
        if (t >= off) u = sh[t - off];
        __syncthreads();
        sh[t] += u;
        __syncthreads();
    }
    int excl = sh[t] - v;
    if (t < NBUCK) { bstart[t] = excl; gcur[t] = excl; }
    if (t == 0) bstart[NBUCK] = NE;
}

__global__ __launch_bounds__(256) void k_partition(const int* __restrict__ srce, const int* __restrict__ dste,
                                                   int* __restrict__ gcur, int* __restrict__ tmp) {
    __shared__ int h[NBUCK], lstart[NBUCK], gbase[NBUCK], scn[256];
    __shared__ int s_pack[P3_CHUNK];
    __shared__ int s_gad[P3_CHUNK];
    const int tid = threadIdx.x;
    const int base = blockIdx.x * P3_CHUNK;
    if (tid < NBUCK) h[tid] = 0;
    __syncthreads();
    int rank[P3_CHUNK / 256];
#pragma unroll
    for (int i = 0; i < P3_CHUNK / 256; i++) {
        int idx = base + i * 256 + tid;
        if (idx < NE) rank[i] = atomicAdd(&h[dste[idx] >> BSH], 1);
    }
    __syncthreads();
    int hv = (tid < NBUCK) ? h[tid] : 0;
    if (tid < NBUCK) gbase[tid] = atomicAdd(&gcur[tid], hv);
    scn[tid] = hv;
    __syncthreads();
    for (int off = 1; off < 256; off <<= 1) {
        int u = 0;
        if (tid >= off) u = scn[tid - off];
        __syncthreads();
        scn[tid] += u;
        __syncthreads();
    }
    if (tid < NBUCK) lstart[tid] = scn[tid] - hv;
    __syncthreads();
#pragma unroll
    for (int i = 0; i < P3_CHUNK / 256; i++) {
        int idx = base + i * 256 + tid;
        if (idx < NE) {
            int d = dste[idx], s = srce[idx];
            int b = d >> BSH;
            int slot = lstart[b] + rank[i];
            s_pack[slot] = (s << BSH) | (d & ((1 << BSH) - 1));
            s_gad[slot] = gbase[b] + rank[i];
        }
    }
    __syncthreads();
    int chunkN = NE - base;
    if (chunkN > P3_CHUNK) chunkN = P3_CHUNK;
#pragma unroll
    for (int i = 0; i < P3_CHUNK / 256; i++) {
        int slot = i * 256 + tid;
        if (slot < chunkN) tmp[s_gad[slot]] = s_pack[slot];
    }
}

__global__ __launch_bounds__(256) void k_bucket(const int* __restrict__ tmp, const int* __restrict__ bstart,
                                                int* __restrict__ row_ptr, int* __restrict__ col,
                                                float* __restrict__ invd) {
    __shared__ int cnt[512], cur[512], scn[256];
    const int b = blockIdx.x, tid = threadIdx.x;
    const int base = bstart[b];
    const int n = bstart[b + 1] - base;
    cnt[tid] = 0;
    cnt[tid + 256] = 0;
    __syncthreads();
    for (int k = tid; k < n; k += 256) atomicAdd(&cnt[tmp[base + k] & 511], 1);
    __syncthreads();
    int c0 = cnt[2 * tid], c1 = cnt[2 * tid + 1], s = c0 + c1;
    scn[tid] = s;
    __syncthreads();
    for (int off = 1; off < 256; off <<= 1) {
        int u = 0;
        if (tid >= off) u = scn[tid - off];
        __syncthreads();
        scn[tid] += u;
        __syncthreads();
    }
    int excl = scn[tid] - s;
    int node = (b << BSH) + 2 * tid;
    if (node < NN) {
        row_ptr[node] = base + excl;
        invd[node] = c0 ? 1.0f / (float)c0 : 0.0f;
    }
    if (node + 1 < NN) {
        row_ptr[node + 1] = base + excl + c0;
        invd[node + 1] = c1 ? 1.0f / (float)c1 : 0.0f;
    }
    cur[2 * tid] = base + excl;
    cur[2 * tid + 1] = base + excl + c0;
    if (b == 0 && tid == 0) row_ptr[NN] = NE;
    __syncthreads();
    for (int k = tid; k < n; k += 256) {
        int p = tmp[base + k];
        int pos = atomicAdd(&cur[p & 511], 1);
        col[pos] = p >> BSH;
    }
}

// ---------------- format conversion ----------------

__global__ __launch_bounds__(256) void k_xsplit(const float* __restrict__ x, unsigned* __restrict__ Xp) {
    int i = blockIdx.x * 256 + threadIdx.x;  // x4 floats
    float4 v = ((const float4*)x)[i];
    uint4 o = {pack_split(v.x), pack_split(v.y), pack_split(v.z), pack_split(v.w)};
    ((uint4*)Xp)[i] = o;
}

// Wp layout (uints): [0:8192) WL0, [8192:16384) WR0, [16384:32768) WL1, [32768:49152) WR1,
// [49152:65536) WPQ (rows 0-63 = Wl2, rows 64-127 = Wr2), [65536:73728) WD1
__global__ __launch_bounds__(256) void k_wsplit(const float* __restrict__ Wl0, const float* __restrict__ Wr0,
                                                const float* __restrict__ Wl1, const float* __restrict__ Wr1,
                                                const float* __restrict__ Wl2, const float* __restrict__ Wr2,
                                                const float* __restrict__ Wd1, const float* __restrict__ bl2,
                                                unsigned* __restrict__ Wp, float* __restrict__ biasPQ) {
    int i = blockIdx.x * 256 + threadIdx.x;
    if (i < 8192) Wp[i] = pack_split(Wl0[i]);
    else if (i < 16384) Wp[i] = pack_split(Wr0[i - 8192]);
    else if (i < 32768) Wp[i] = pack_split(Wl1[i - 16384]);
    else if (i < 49152) Wp[i] = pack_split(Wr1[i - 32768]);
    else if (i < 57344) Wp[i] = pack_split(Wl2[i - 49152]);
    else if (i < 65536) Wp[i] = pack_split(Wr2[i - 57344]);
    else if (i < 73728) Wp[i] = pack_split(Wd1[i - 65536]);
    else if (i < 73856) {
        int j = i - 73728;
        biasPQ[j] = (j < 64) ? 0.f : bl2[j - 64];
    }
}

// ---------------- aggregation (one wave per node, 8-deep MLP) ----------------

// L0: gather x fp32 (ld 64) -> packed out (ld 64)
__global__ __launch_bounds__(256) void k_agg64(const float* __restrict__ h, const int* __restrict__ row_ptr,
                                               const int* __restrict__ col, const float* __restrict__ inv_deg,
                                               unsigned* __restrict__ agg) {
    int node = blockIdx.x * 4 + (threadIdx.x >> 6);
    int lane = threadIdx.x & 63;
    int start = row_ptr[node], end = row_ptr[node + 1];
    float a0 = 0.f, a1 = 0.f, a2 = 0.f, a3 = 0.f, a4 = 0.f, a5 = 0.f, a6 = 0.f, a7 = 0.f;
    for (int cs = start; cs < end; cs += 64) {
        int n = end - cs;
        if (n > 64) n = 64;
        int my = (lane < n) ? col[cs + lane] : 0;
        int j = 0;
        for (; j + 8 <= n; j += 8) {
            int s0 = __shfl(my, j + 0), s1 = __shfl(my, j + 1);
            int s2 = __shfl(my, j + 2), s3 = __shfl(my, j + 3);
            int s4 = __shfl(my, j + 4), s5 = __shfl(my, j + 5);
            int s6 = __shfl(my, j + 6), s7 = __shfl(my, j + 7);
            float v0 = h[(size_t)s0 * 64 + lane];
            float v1 = h[(size_t)s1 * 64 + lane];
            float v2 = h[(size_t)s2 * 64 + lane];
            float v3 = h[(size_t)s3 * 64 + lane];
            float v4 = h[(size_t)s4 * 64 + lane];
            float v5 = h[(size_t)s5 * 64 + lane];
            float v6 = h[(size_t)s6 * 64 + lane];
            float v7 = h[(size_t)s7 * 64 + lane];
            a0 += v0; a1 += v1; a2 += v2; a3 += v3;
            a4 += v4; a5 += v5; a6 += v6; a7 += v7;
        }
        for (; j < n; j++) {
            int s = __shfl(my, j);
            a0 += h[(size_t)s * 64 + lane];
        }
    }
    float acc = ((a0 + a1) + (a2 + a3)) + ((a4 + a5) + (a6 + a7));
    agg[(size_t)node * 64 + lane] = pack_split(acc * inv_deg[node]);
}

// L1: gather packed (ld 128) -> packed out (ld 128)
__global__ __launch_bounds__(256) void k_agg128p(const unsigned* __restrict__ hp, const int* __restrict__ row_ptr,
                                                 const int* __restrict__ col, const float* __restrict__ inv_deg,
                                                 unsigned* __restrict__ agg) {
    int node = blockIdx.x * 4 + (threadIdx.x >> 6);
    int lane = threadIdx.x & 63;
    int start = row_ptr[node], end = row_ptr[node + 1];
    const uint2* h2 = (const uint2*)hp;  // row stride 64 uint2
    float ax0 = 0.f, ax1 = 0.f, ax2 = 0.f, ax3 = 0.f, ax4 = 0.f, ax5 = 0.f, ax6 = 0.f, ax7 = 0.f;
    float ay0 = 0.f, ay1 = 0.f, ay2 = 0.f, ay3 = 0.f, ay4 = 0.f, ay5 = 0.f, ay6 = 0.f, ay7 = 0.f;
    for (int cs = start; cs < end; cs += 64) {
        int n = end - cs;
        if (n > 64) n = 64;
        int my = (lane < n) ? col[cs + lane] : 0;
        int j = 0;
        for (; j + 8 <= n; j += 8) {
            int s0 = __shfl(my, j + 0), s1 = __shfl(my, j + 1);
            int s2 = __shfl(my, j + 2), s3 = __shfl(my, j + 3);
            int s4 = __shfl(my, j + 4), s5 = __shfl(my, j + 5);
            int s6 = __shfl(my, j + 6), s7 = __shfl(my, j + 7);
            uint2 u0 = h2[(size_t)s0 * 64 + lane];
            uint2 u1 = h2[(size_t)s1 * 64 + lane];
            uint2 u2 = h2[(size_t)s2 * 64 + lane];
            uint2 u3 = h2[(size_t)s3 * 64 + lane];
            uint2 u4 = h2[(size_t)s4 * 64 + lane];
            uint2 u5 = h2[(size_t)s5 * 64 + lane];
            uint2 u6 = h2[(size_t)s6 * 64 + lane];
            uint2 u7 = h2[(size_t)s7 * 64 + lane];
            ax0 += rec_sum(u0.x); ay0 += rec_sum(u0.y);
            ax1 += rec_sum(u1.x); ay1 += rec_sum(u1.y);
            ax2 += rec_sum(u2.x); ay2 += rec_sum(u2.y);
            ax3 += rec_sum(u3.x); ay3 += rec_sum(u3.y);
            ax4 += rec_sum(u4.x); ay4 += rec_sum(u4.y);
            ax5 += rec_sum(u5.x); ay5 += rec_sum(u5.y);
            ax6 += rec_sum(u6.x); ay6 += rec_sum(u6.y);
            ax7 += rec_sum(u7.x); ay7 += rec_sum(u7.y);
        }
        for (; j < n; j++) {
            int s = __shfl(my, j);
            uint2 u = h2[(size_t)s * 64 + lane];
            ax0 += rec_sum(u.x);
            ay0 += rec_sum(u.y);
        }
    }
    float w = inv_deg[node];
    float sx = (((ax0 + ax1) + (ax2 + ax3)) + ((ax4 + ax5) + (ax6 + ax7))) * w;
    float sy = (((ay0 + ay1) + (ay2 + ay3)) + ((ay4 + ay5) + (ay6 + ay7))) * w;
    uint2 o = {pack_split(sx), pack_split(sy)};
    *((uint2*)agg + (size_t)node * 64 + lane) = o;
}

// L2 tail: h2 = relu(Q + invd * sum P[s]); P = PQ[:, 0:64], Q = PQ[:, 64:128] (fp32, ld 128)
__global__ __launch_bounds__(256) void k_agg_relu64p(const float* __restrict__ PQ, const int* __restrict__ row_ptr,
                                                     const int* __restrict__ col, const float* __restrict__ inv_deg,
                                                     unsigned* __restrict__ out) {
    int node = blockIdx.x * 4 + (threadIdx.x >> 6);
    int lane = threadIdx.x & 63;
    int start = row_ptr[node], end = row_ptr[node + 1];
    float a0 = 0.f, a1 = 0.f, a2 = 0.f, a3 = 0.f, a4 = 0.f, a5 = 0.f, a6 = 0.f, a7 = 0.f;
    for (int cs = start; cs < end; cs += 64) {
        int n = end - cs;
        if (n > 64) n = 64;
        int my = (lane < n) ? col[cs + lane] : 0;
        int j = 0;
        for (; j + 8 <= n; j += 8) {
            int s0 = __shfl(my, j + 0), s1 = __shfl(my, j + 1);
            int s2 = __shfl(my, j + 2), s3 = __shfl(my, j + 3);
            int s4 = __shfl(my, j + 4), s5 = __shfl(my, j + 5);
            int s6 = __shfl(my, j + 6), s7 = __shfl(my, j + 7);
            float v0 = PQ[(size_t)s0 * 128 + lane];
            float v1 = PQ[(size_t)s1 * 128 + lane];
            float v2 = PQ[(size_t)s2 * 128 + lane];
            float v3 = PQ[(size_t)s3 * 128 + lane];
            float v4 = PQ[(size_t)s4 * 128 + lane];
            float v5 = PQ[(size_t)s5 * 128 + lane];
            float v6 = PQ[(size_t)s6 * 128 + lane];
            float v7 = PQ[(size_t)s7 * 128 + lane];
            a0 += v0; a1 += v1; a2 += v2; a3 += v3;
            a4 += v4; a5 += v5; a6 += v6; a7 += v7;
        }
        for (; j < n; j++) {
            int s = __shfl(my, j);
            a0 += PQ[(size_t)s * 128 + lane];
        }
    }
    float acc = ((a0 + a1) + (a2 + a3)) + ((a4 + a5) + (a6 + a7));
    float v = PQ[(size_t)node * 128 + 64 + lane] + inv_deg[node] * acc;
    out[(size_t)node * 64 + lane] = pack_split(fmaxf(v, 0.f));
}

// ---------------- split-bf16 MFMA GEMM ----------------
// C[M x 128] = A1@W1^T (+ A2@W2^T) + bias, split-bf16 via 3 MFMA passes.
// BM=128, BN=128, BK=32. 256 threads = 4 waves (2x2), each wave 64x64 (4x4 16x16 tiles).
// LDS: interleaved packed uints, row stride 36 (16B pad) -> uniform bank load.

#define LDL 36

template <int K>
__device__ inline void mg_phase(const unsigned* __restrict__ A, const unsigned* __restrict__ W,
                                int m0, unsigned* Al, unsigned* Bl, f32x4 (&acc)[4][4],
                                int tid, int wm, int wn, int l15, int quad) {
    const int srow = tid >> 1, scol = (tid & 1) * 16;
#pragma unroll 1
    for (int kt = 0; kt < K; kt += 32) {
        __syncthreads();
        uint4 a0 = {0, 0, 0, 0}, a1 = {0, 0, 0, 0}, a2 = {0, 0, 0, 0}, a3 = {0, 0, 0, 0};
        int gr = m0 + srow;
        if (gr < NN) {
            const uint4* p = (const uint4*)(A + (size_t)gr * K + kt + scol);
            a0 = p[0]; a1 = p[1]; a2 = p[2]; a3 = p[3];
        }
        const uint4* q = (const uint4*)(W + srow * K + kt + scol);
        uint4 b0 = q[0], b1 = q[1], b2 = q[2], b3 = q[3];
        uint4* da = (uint4*)(Al + srow * LDL + scol);
        da[0] = a0; da[1] = a1; da[2] = a2; da[3] = a3;
        uint4* db = (uint4*)(Bl + srow * LDL + scol);
        db[0] = b0; db[1] = b1; db[2] = b2; db[3] = b3;
        __syncthreads();
        short8 ah[4], al[4], bh[4], bl[4];
#pragma unroll
        for (int t = 0; t < 4; t++) {
            frag_extract(Al + (wm + t * 16 + l15) * LDL + quad * 8, ah[t], al[t]);
            frag_extract(Bl + (wn + t * 16 + l15) * LDL + quad * 8, bh[t], bl[t]);
        }
#pragma unroll
        for (int mt = 0; mt < 4; mt++)
#pragma unroll
            for (int nt = 0; nt < 4; nt++) {
                acc[mt][nt] = __builtin_amdgcn_mfma_f32_16x16x32_bf16(ah[mt], bh[nt], acc[mt][nt], 0, 0, 0);
                acc[mt][nt] = __builtin_amdgcn_mfma_f32_16x16x32_bf16(ah[mt], bl[nt], acc[mt][nt], 0, 0, 0);
                acc[mt][nt] = __builtin_amdgcn_mfma_f32_16x16x32_bf16(al[mt], bh[nt], acc[mt][nt], 0, 0, 0);
            }
    }
}

// OMODE: 0 = fp32 out, 1 = packed split out. ldc fixed 128.
// In-place C == A2 is safe: each block writes only its own rows, after all its reads.
template <int K1, int K2, bool RELU, int OMODE>
__global__ __launch_bounds__(256) void k_mgemm(const unsigned* __restrict__ A1, const unsigned* __restrict__ W1,
                                               const unsigned* A2, const unsigned* __restrict__ W2,
                                               const float* __restrict__ bias, float* Cf, unsigned* Cp) {
    __shared__ unsigned Al[128 * LDL];
    __shared__ unsigned Bl[128 * LDL];
    const int tid = threadIdx.x;
    const int m0 = blockIdx.x * 128;
    const int wave = tid >> 6, lane = tid & 63;
    const int wm = (wave & 1) * 64, wn = (wave >> 1) * 64;
    const int l15 = lane & 15, quad = lane >> 4;
    f32x4 acc[4][4];
#pragma unroll
    for (int i = 0; i < 4; i++)
#pragma unroll
        for (int j = 0; j < 4; j++) acc[i][j] = (f32x4){0.f, 0.f, 0.f, 0.f};

    mg_phase<K1>(A1, W1, m0, Al, Bl, acc, tid, wm, wn, l15, quad);
    if (K2 > 0) mg_phase<K2>(A2, W2, m0, Al, Bl, acc, tid, wm, wn, l15, quad);

#pragma unroll
    for (int mt = 0; mt < 4; mt++) {
        int rbase = m0 + wm + mt * 16 + quad * 4;
#pragma unroll
        for (int nt = 0; nt < 4; nt++) {
            int cg = wn + nt * 16 + l15;
            float bv = bias[cg];
#pragma unroll
            for (int r = 0; r < 4; r++) {
                int row = rbase + r;
                if (row < NN) {
                    float v = acc[mt][nt][r] + bv;
                    if (RELU) v = fmaxf(v, 0.f);
                    if (OMODE == 0) Cf[(size_t)row * 128 + cg] = v;
                    else Cp[(size_t)row * 128 + cg] = pack_split(v);
                }
            }
        }
    }
}

// ---------------- final decoder layer ----------------

__global__ __launch_bounds__(256) void k_dec2(const float* __restrict__ h, const float* __restrict__ W,
                                              const float* __restrict__ b, float* __restrict__ out) {
    int node = blockIdx.x * 4 + (threadIdx.x >> 6);
    int lane = threadIdx.x & 63;
    float2 hv = *((const float2*)(h + (size_t)node * 128) + lane);
    float d0 = hv.x * W[2 * lane] + hv.y * W[2 * lane + 1];
    float d1 = hv.x * W[128 + 2 * lane] + hv.y * W[128 + 2 * lane + 1];
    for (int off = 32; off > 0; off >>= 1) {
        d0 += __shfl_down(d0, off);
        d1 += __shfl_down(d1, off);
    }
    if (lane == 0) {
        out[(size_t)node * 2 + 0] = d0 + b[0];
        out[(size_t)node * 2 + 1] = d1 + b[1];
    }
}

// ---------------- launch ----------------

extern "C" void kernel_launch(void* const* d_in, const int* in_sizes, int n_in,
                              void* d_out, int out_size, void* d_ws, size_t ws_size,
                              hipStream_t stream) {
    const float* x   = (const float*)d_in[0];
    const int*   ei  = (const int*)d_in[1];
    const float* Wl0 = (const float*)d_in[2];
    const float* bl0 = (const float*)d_in[3];
    const float* Wr0 = (const float*)d_in[4];
    const float* Wl1 = (const float*)d_in[5];
    const float* bl1 = (const float*)d_in[6];
    const float* Wr1 = (const float*)d_in[7];
    const float* Wl2 = (const float*)d_in[8];
    const float* bl2 = (const float*)d_in[9];
    const float* Wr2 = (const float*)d_in[10];
    const float* Wd1 = (const float*)d_in[11];
    const float* bd1 = (const float*)d_in[12];
    const float* Wd2 = (const float*)d_in[13];
    const float* bd2 = (const float*)d_in[14];
    float* out = (float*)d_out;

    char* ws = (char*)d_ws;
    size_t off = 0;
    auto alloc = [&](size_t bytes) {
        char* p = ws + off;
        off = (off + bytes + 255) & ~(size_t)255;
        return p;
    };
    int*      bcnt    = (int*)alloc((size_t)NBUCK * 4);
    int*      bstart  = (int*)alloc((size_t)(NBUCK + 1) * 4);
    int*      gcur    = (int*)alloc((size_t)NBUCK * 4);
    int*      row_ptr = (int*)alloc((size_t)(NN + 1) * 4);
    float*    invd    = (float*)alloc((size_t)NN * 4);
    int*      col     = (int*)alloc((size_t)NE * 4);
    unsigned* Wp      = (unsigned*)alloc((size_t)73728 * 4);
    float*    biasPQ  = (float*)alloc(128 * 4);
    unsigned* S1      = (unsigned*)alloc((size_t)NN * 128 * 4);
    unsigned* S2      = (unsigned*)alloc((size_t)NN * 128 * 4);
    (void)ws_size;

    // aliases (lifetime-checked):
    int*      tmp   = (int*)S2;              // CSR scratch, dead before S2's first write (G0p)
    unsigned* Xp    = S1;                    // x packed           [NN][64]
    unsigned* Agg0p = S1 + (size_t)NN * 64;  // L0 agg packed      [NN][64]
    unsigned* G0p   = S2;                    // L0 out packed      [NN][128]
    unsigned* Agg1p = S1;                    // L1 agg packed      [NN][128] (Xp/Agg0p dead)
    unsigned* H1p   = S2;                    // L1 out, in-place over G0p
    float*    PQ    = (float*)S1;            // [P|Q] fp32         [NN][128] (Agg1p dead)
    unsigned* h2p   = S2;                    // layer-2 out packed [NN][64]  (H1p dead)
    float*    d1    = (float*)S1;            // decoder hidden     [NN][128] (PQ dead)

    const unsigned* WL0p = Wp;
    const unsigned* WR0p = Wp + 8192;
    const unsigned* WL1p = Wp + 16384;
    const unsigned* WR1p = Wp + 32768;
    const unsigned* WPQp = Wp + 49152;
    const unsigned* WD1p = Wp + 65536;

    const int* srce = ei;
    const int* dste = ei + NE;

    // CSR build
    k_zero_small<<<1, 256, 0, stream>>>(bcnt, NBUCK);
    k_hist<<<400, 256, 0, stream>>>(dste, bcnt);
    k_bscan<<<1, 256, 0, stream>>>(bcnt, bstart, gcur);
    k_partition<<<P3_BLOCKS, 256, 0, stream>>>(srce, dste, gcur, tmp);
    k_bucket<<<NBUCK, 256, 0, stream>>>(tmp, bstart, row_ptr, col, invd);

    // format conversion
    k_wsplit<<<289, 256, 0, stream>>>(Wl0, Wr0, Wl1, Wr1, Wl2, Wr2, Wd1, bl2, Wp, biasPQ);
    k_xsplit<<<(NN * 64 / 4 + 255) / 256, 256, 0, stream>>>(x, Xp);

    const int gGemm = (NN + 127) / 128;  // 782
    const int gNode = NN / 4;            // 25000

    // Layer 0: 64 -> 128, ReLU
    k_agg64<<<gNode, 256, 0, stream>>>(x, row_ptr, col, invd, Agg0p);
    k_mgemm<64, 64, true, 1><<<gGemm, 256, 0, stream>>>(Agg0p, WL0p, Xp, WR0p, bl0, nullptr, G0p);

    // Layer 1: 128 -> 128, ReLU (in-place over G0p)
    k_agg128p<<<gNode, 256, 0, stream>>>(G0p, row_ptr, col, invd, Agg1p);
    k_mgemm<128, 128, true, 1><<<gGemm, 256, 0, stream>>>(Agg1p, WL1p, G0p, WR1p, bl1, nullptr, H1p);

    // Layer 2 (transform-before-aggregate): PQ = h1 @ [Wl2;Wr2]^T + [0;bl2]
    k_mgemm<128, 0, false, 0><<<gGemm, 256, 0, stream>>>(H1p, WPQp, nullptr, nullptr, biasPQ, PQ, nullptr);
    k_agg_relu64p<<<gNode, 256, 0, stream>>>(PQ, row_ptr, col, invd, h2p);

    // Decoder: 64 -> 128 (ReLU) -> 2
    k_mgemm<64, 0, true, 0><<<gGemm, 256, 0, stream>>>(h2p, WD1p, nullptr, nullptr, bd1, d1, nullptr);
    k_dec2<<<gNode, 256, 0, stream>>>(d1, Wd2, bd2, out);
}

// Round 5
// 488.489 us; speedup vs baseline: 1.8716x; 1.1225x over previous
//
#include <hip/hip_runtime.h>
#include <cstdint>
#include <cstddef>

#define NN 100000
#define NE 1600000
#define BSH 9
#define NBUCK 196          // ceil(NN / 512)
#define P3_CHUNK 8192
#define P3_BLOCKS 196      // ceil(NE / P3_CHUNK)

typedef __attribute__((ext_vector_type(8))) short short8;
typedef __attribute__((ext_vector_type(4))) float f32x4;

// ---------------- split-bf16 helpers ----------------
// pack_split(v): bits[15:0] = hi bf16 (RN), bits[31:16] = lo bf16 (RN of residual); v ~= hi + lo

__device__ inline unsigned pack_split(float v) {
    unsigned u = __builtin_bit_cast(unsigned, v);
    unsigned hi = (u + 0x7fffu + ((u >> 16) & 1u)) >> 16;
    float vh = __builtin_bit_cast(float, hi << 16);
    float r = v - vh;
    unsigned u2 = __builtin_bit_cast(unsigned, r);
    unsigned lo = (u2 + 0x7fffu + ((u2 >> 16) & 1u)) >> 16;
    return hi | (lo << 16);
}

__device__ inline unsigned short rnb(float v) {  // RN-even bf16
    unsigned u = __builtin_bit_cast(unsigned, v);
    return (unsigned short)((u + 0x7fffu + ((u >> 16) & 1u)) >> 16);
}

__device__ inline float bf2f(unsigned short u) {
    return __builtin_bit_cast(float, (unsigned)u << 16);
}

// ---------------- CSR build via LDS-staged counting sort ----------------

__global__ __launch_bounds__(256) void k_zero_small(int* p, int n) {
    for (int i = threadIdx.x; i < n; i += 256) p[i] = 0;
}

__global__ __launch_bounds__(256) void k_hist(const int* __restrict__ dst, int* __restrict__ bcnt) {
    __shared__ int h[NBUCK];
    const int tid = threadIdx.x;
    if (tid < NBUCK) h[tid] = 0;
    __syncthreads();
    for (int e = blockIdx.x * 256 + tid; e < NE; e += gridDim.x * 256)
        atomicAdd(&h[dst[e] >> BSH], 1);
    __syncthreads();
    if (tid < NBUCK) atomicAdd(&bcnt[tid], h[tid]);
}

__global__ __launch_bounds__(256) void k_bscan(const int* __restrict__ bcnt, int* __restrict__ bstart,
                                               int* __restrict__ gcur) {
    __shared__ int sh[256];
    const int t = threadIdx.x;
    int v = (t < NBUCK) ? bcnt[t] : 0;
    sh[t] = v;
    __syncthreads();
    for (int off = 1; off < 256; off <<= 1) {
        int u = 0;
        if (t >= off) u = sh[t - off];
        __syncthreads();
        sh[t] += u;
        __syncthreads();
    }
    int excl = sh[t] - v;
    if (t < NBUCK) { bstart[t] = excl; gcur[t] = excl; }
    if (t == 0) bstart[NBUCK] = NE;
}

__global__ __launch_bounds__(256) void k_partition(const int* __restrict__ srce, const int* __restrict__ dste,
                                                   int* __restrict__ gcur, int* __restrict__ tmp) {
    __shared__ int h[NBUCK], lstart[NBUCK], gbase[NBUCK], scn[256];
    __shared__ int s_pack[P3_CHUNK];
    __shared__ int s_gad[P3_CHUNK];
    const int tid = threadIdx.x;
    const int base = blockIdx.x * P3_CHUNK;
    if (tid < NBUCK) h[tid] = 0;
    __syncthreads();
    int rank[P3_CHUNK / 256];
#pragma unroll
    for (int i = 0; i < P3_CHUNK / 256; i++) {
        int idx = base + i * 256 + tid;
        if (idx < NE) rank[i] = atomicAdd(&h[dste[idx] >> BSH], 1);
    }
    __syncthreads();
    int hv = (tid < NBUCK) ? h[tid] : 0;
    if (tid < NBUCK) gbase[tid] = atomicAdd(&gcur[tid], hv);
    scn[tid] = hv;
    __syncthreads();
    for (int off = 1; off < 256; off <<= 1) {
        int u = 0;
        if (tid >= off) u = scn[tid - off];
        __syncthreads();
        scn[tid] += u;
        __syncthreads();
    }
    if (tid < NBUCK) lstart[tid] = scn[tid] - hv;
    __syncthreads();
#pragma unroll
    for (int i = 0; i < P3_CHUNK / 256; i++) {
        int idx = base + i * 256 + tid;
        if (idx < NE) {
            int d = dste[idx], s = srce[idx];
            int b = d >> BSH;
            int slot = lstart[b] + rank[i];
            s_pack[slot] = (s << BSH) | (d & ((1 << BSH) - 1));
            s_gad[slot] = gbase[b] + rank[i];
        }
    }
    __syncthreads();
    int chunkN = NE - base;
    if (chunkN > P3_CHUNK) chunkN = P3_CHUNK;
#pragma unroll
    for (int i = 0; i < P3_CHUNK / 256; i++) {
        int slot = i * 256 + tid;
        if (slot < chunkN) tmp[s_gad[slot]] = s_pack[slot];
    }
}

__global__ __launch_bounds__(256) void k_bucket(const int* __restrict__ tmp, const int* __restrict__ bstart,
                                                int* __restrict__ row_ptr, int* __restrict__ col,
                                                float* __restrict__ invd) {
    __shared__ int cnt[512], cur[512], scn[256];
    const int b = blockIdx.x, tid = threadIdx.x;
    const int base = bstart[b];
    const int n = bstart[b + 1] - base;
    cnt[tid] = 0;
    cnt[tid + 256] = 0;
    __syncthreads();
    for (int k = tid; k < n; k += 256) atomicAdd(&cnt[tmp[base + k] & 511], 1);
    __syncthreads();
    int c0 = cnt[2 * tid], c1 = cnt[2 * tid + 1], s = c0 + c1;
    scn[tid] = s;
    __syncthreads();
    for (int off = 1; off < 256; off <<= 1) {
        int u = 0;
        if (tid >= off) u = scn[tid - off];
        __syncthreads();
        scn[tid] += u;
        __syncthreads();
    }
    int excl = scn[tid] - s;
    int node = (b << BSH) + 2 * tid;
    if (node < NN) {
        row_ptr[node] = base + excl;
        invd[node] = c0 ? 1.0f / (float)c0 : 0.0f;
    }
    if (node + 1 < NN) {
        row_ptr[node + 1] = base + excl + c0;
        invd[node + 1] = c1 ? 1.0f / (float)c1 : 0.0f;
    }
    cur[2 * tid] = base + excl;
    cur[2 * tid + 1] = base + excl + c0;
    if (b == 0 && tid == 0) row_ptr[NN] = NE;
    __syncthreads();
    for (int k = tid; k < n; k += 256) {
        int p = tmp[base + k];
        int pos = atomicAdd(&cur[p & 511], 1);
        col[pos] = p >> BSH;
    }
}

// ---------------- format conversion ----------------

__global__ __launch_bounds__(256) void k_xhi(const float* __restrict__ x, unsigned short* __restrict__ Xh) {
    int i = blockIdx.x * 256 + threadIdx.x;  // x4 elems
    float4 v = ((const float4*)x)[i];
    ushort4 o = {rnb(v.x), rnb(v.y), rnb(v.z), rnb(v.w)};
    ((ushort4*)Xh)[i] = o;
}

// weight planes layout (ushort index): [0:8192) WL0, [8192:16384) WR0, [16384:32768) WL1,
// [32768:49152) WR1, [49152:65536) WPQ (rows 0-63 Wl2, 64-127 Wr2), [65536:73728) WD1
__global__ __launch_bounds__(256) void k_wsplit(const float* __restrict__ Wl0, const float* __restrict__ Wr0,
                                                const float* __restrict__ Wl1, const float* __restrict__ Wr1,
                                                const float* __restrict__ Wl2, const float* __restrict__ Wr2,
                                                const float* __restrict__ Wd1, const float* __restrict__ bl2,
                                                unsigned short* __restrict__ Wh, unsigned short* __restrict__ Wl,
                                                float* __restrict__ biasPQ) {
    int i = blockIdx.x * 256 + threadIdx.x;
    float v = 0.f;
    bool valid = true;
    if (i < 8192) v = Wl0[i];
    else if (i < 16384) v = Wr0[i - 8192];
    else if (i < 32768) v = Wl1[i - 16384];
    else if (i < 49152) v = Wr1[i - 32768];
    else if (i < 57344) v = Wl2[i - 49152];
    else if (i < 65536) v = Wr2[i - 57344];
    else if (i < 73728) v = Wd1[i - 65536];
    else valid = false;
    if (valid) {
        unsigned ps = pack_split(v);
        Wh[i] = (unsigned short)ps;
        Wl[i] = (unsigned short)(ps >> 16);
    }
    if (i >= 73728 && i < 73856) {
        int j = i - 73728;
        biasPQ[j] = (j < 64) ? 0.f : bl2[j - 64];
    }
}

// ---------------- aggregation (one wave per node, 8-deep MLP, bf16-hi gather) ----------------

// L0: gather Xh (bf16, [NN][64]) -> Agg0 planes
__global__ __launch_bounds__(256) void k_agg64h(const unsigned short* __restrict__ Xh, const int* __restrict__ row_ptr,
                                                const int* __restrict__ col, const float* __restrict__ invd,
                                                unsigned short* __restrict__ Ah, unsigned short* __restrict__ Al) {
    int node = blockIdx.x * 4 + (threadIdx.x >> 6);
    int lane = threadIdx.x & 63;
    int start = row_ptr[node], end = row_ptr[node + 1];
    float a0 = 0.f, a1 = 0.f, a2 = 0.f, a3 = 0.f, a4 = 0.f, a5 = 0.f, a6 = 0.f, a7 = 0.f;
    for (int cs = start; cs < end; cs += 64) {
        int n = end - cs;
        if (n > 64) n = 64;
        int my = (lane < n) ? col[cs + lane] : 0;
        int j = 0;
        for (; j + 8 <= n; j += 8) {
            int s0 = __shfl(my, j + 0), s1 = __shfl(my, j + 1);
            int s2 = __shfl(my, j + 2), s3 = __shfl(my, j + 3);
            int s4 = __shfl(my, j + 4), s5 = __shfl(my, j + 5);
            int s6 = __shfl(my, j + 6), s7 = __shfl(my, j + 7);
            float v0 = bf2f(Xh[(size_t)s0 * 64 + lane]);
            float v1 = bf2f(Xh[(size_t)s1 * 64 + lane]);
            float v2 = bf2f(Xh[(size_t)s2 * 64 + lane]);
            float v3 = bf2f(Xh[(size_t)s3 * 64 + lane]);
            float v4 = bf2f(Xh[(size_t)s4 * 64 + lane]);
            float v5 = bf2f(Xh[(size_t)s5 * 64 + lane]);
            float v6 = bf2f(Xh[(size_t)s6 * 64 + lane]);
            float v7 = bf2f(Xh[(size_t)s7 * 64 + lane]);
            a0 += v0; a1 += v1; a2 += v2; a3 += v3;
            a4 += v4; a5 += v5; a6 += v6; a7 += v7;
        }
        for (; j < n; j++) {
            int s = __shfl(my, j);
            a0 += bf2f(Xh[(size_t)s * 64 + lane]);
        }
    }
    float acc = ((a0 + a1) + (a2 + a3)) + ((a4 + a5) + (a6 + a7));
    unsigned ps = pack_split(acc * invd[node]);
    Ah[(size_t)node * 64 + lane] = (unsigned short)ps;
    Al[(size_t)node * 64 + lane] = (unsigned short)(ps >> 16);
}

// L1: gather G0hi (bf16, [NN][128], lane covers cols 2*lane, 2*lane+1) -> Agg1 planes
__global__ __launch_bounds__(256) void k_agg128h(const unsigned short* __restrict__ Gh, const int* __restrict__ row_ptr,
                                                 const int* __restrict__ col, const float* __restrict__ invd,
                                                 unsigned short* __restrict__ Ah, unsigned short* __restrict__ Al) {
    int node = blockIdx.x * 4 + (threadIdx.x >> 6);
    int lane = threadIdx.x & 63;
    int start = row_ptr[node], end = row_ptr[node + 1];
    float ax0 = 0.f, ax1 = 0.f, ax2 = 0.f, ax3 = 0.f, ax4 = 0.f, ax5 = 0.f, ax6 = 0.f, ax7 = 0.f;
    float ay0 = 0.f, ay1 = 0.f, ay2 = 0.f, ay3 = 0.f, ay4 = 0.f, ay5 = 0.f, ay6 = 0.f, ay7 = 0.f;
    for (int cs = start; cs < end; cs += 64) {
        int n = end - cs;
        if (n > 64) n = 64;
        int my = (lane < n) ? col[cs + lane] : 0;
        int j = 0;
        for (; j + 8 <= n; j += 8) {
            int s0 = __shfl(my, j + 0), s1 = __shfl(my, j + 1);
            int s2 = __shfl(my, j + 2), s3 = __shfl(my, j + 3);
            int s4 = __shfl(my, j + 4), s5 = __shfl(my, j + 5);
            int s6 = __shfl(my, j + 6), s7 = __shfl(my, j + 7);
            unsigned u0 = *(const unsigned*)(Gh + (size_t)s0 * 128 + 2 * lane);
            unsigned u1 = *(const unsigned*)(Gh + (size_t)s1 * 128 + 2 * lane);
            unsigned u2 = *(const unsigned*)(Gh + (size_t)s2 * 128 + 2 * lane);
            unsigned u3 = *(const unsigned*)(Gh + (size_t)s3 * 128 + 2 * lane);
            unsigned u4 = *(const unsigned*)(Gh + (size_t)s4 * 128 + 2 * lane);
            unsigned u5 = *(const unsigned*)(Gh + (size_t)s5 * 128 + 2 * lane);
            unsigned u6 = *(const unsigned*)(Gh + (size_t)s6 * 128 + 2 * lane);
            unsigned u7 = *(const unsigned*)(Gh + (size_t)s7 * 128 + 2 * lane);
            ax0 += bf2f((unsigned short)u0); ay0 += bf2f((unsigned short)(u0 >> 16));
            ax1 += bf2f((unsigned short)u1); ay1 += bf2f((unsigned short)(u1 >> 16));
            ax2 += bf2f((unsigned short)u2); ay2 += bf2f((unsigned short)(u2 >> 16));
            ax3 += bf2f((unsigned short)u3); ay3 += bf2f((unsigned short)(u3 >> 16));
            ax4 += bf2f((unsigned short)u4); ay4 += bf2f((unsigned short)(u4 >> 16));
            ax5 += bf2f((unsigned short)u5); ay5 += bf2f((unsigned short)(u5 >> 16));
            ax6 += bf2f((unsigned short)u6); ay6 += bf2f((unsigned short)(u6 >> 16));
            ax7 += bf2f((unsigned short)u7); ay7 += bf2f((unsigned short)(u7 >> 16));
        }
        for (; j < n; j++) {
            int s = __shfl(my, j);
            unsigned u = *(const unsigned*)(Gh + (size_t)s * 128 + 2 * lane);
            ax0 += bf2f((unsigned short)u);
            ay0 += bf2f((unsigned short)(u >> 16));
        }
    }
    float w = invd[node];
    float sx = (((ax0 + ax1) + (ax2 + ax3)) + ((ax4 + ax5) + (ax6 + ax7))) * w;
    float sy = (((ay0 + ay1) + (ay2 + ay3)) + ((ay4 + ay5) + (ay6 + ay7))) * w;
    unsigned px = pack_split(sx), py = pack_split(sy);
    *(unsigned*)(Ah + (size_t)node * 128 + 2 * lane) = (px & 0xffffu) | (py << 16);
    *(unsigned*)(Al + (size_t)node * 128 + 2 * lane) = (px >> 16) | (py & 0xffff0000u);
}

// L2 tail: h2 = relu(Q + invd * sum Ph[s]) -> h2 planes
__global__ __launch_bounds__(256) void k_aggPh(const unsigned short* __restrict__ Ph, const float* __restrict__ Qf,
                                               const int* __restrict__ row_ptr, const int* __restrict__ col,
                                               const float* __restrict__ invd,
                                               unsigned short* __restrict__ Hh, unsigned short* __restrict__ Hl) {
    int node = blockIdx.x * 4 + (threadIdx.x >> 6);
    int lane = threadIdx.x & 63;
    int start = row_ptr[node], end = row_ptr[node + 1];
    float a0 = 0.f, a1 = 0.f, a2 = 0.f, a3 = 0.f, a4 = 0.f, a5 = 0.f, a6 = 0.f, a7 = 0.f;
    for (int cs = start; cs < end; cs += 64) {
        int n = end - cs;
        if (n > 64) n = 64;
        int my = (lane < n) ? col[cs + lane] : 0;
        int j = 0;
        for (; j + 8 <= n; j += 8) {
            int s0 = __shfl(my, j + 0), s1 = __shfl(my, j + 1);
            int s2 = __shfl(my, j + 2), s3 = __shfl(my, j + 3);
            int s4 = __shfl(my, j + 4), s5 = __shfl(my, j + 5);
            int s6 = __shfl(my, j + 6), s7 = __shfl(my, j + 7);
            float v0 = bf2f(Ph[(size_t)s0 * 64 + lane]);
            float v1 = bf2f(Ph[(size_t)s1 * 64 + lane]);
            float v2 = bf2f(Ph[(size_t)s2 * 64 + lane]);
            float v3 = bf2f(Ph[(size_t)s3 * 64 + lane]);
            float v4 = bf2f(Ph[(size_t)s4 * 64 + lane]);
            float v5 = bf2f(Ph[(size_t)s5 * 64 + lane]);
            float v6 = bf2f(Ph[(size_t)s6 * 64 + lane]);
            float v7 = bf2f(Ph[(size_t)s7 * 64 + lane]);
            a0 += v0; a1 += v1; a2 += v2; a3 += v3;
            a4 += v4; a5 += v5; a6 += v6; a7 += v7;
        }
        for (; j < n; j++) {
            int s = __shfl(my, j);
            a0 += bf2f(Ph[(size_t)s * 64 + lane]);
        }
    }
    float acc = ((a0 + a1) + (a2 + a3)) + ((a4 + a5) + (a6 + a7));
    float v = Qf[(size_t)node * 64 + lane] + invd[node] * acc;
    unsigned ps = pack_split(fmaxf(v, 0.f));
    Hh[(size_t)node * 64 + lane] = (unsigned short)ps;
    Hl[(size_t)node * 64 + lane] = (unsigned short)(ps >> 16);
}

// ---------------- planar split-bf16 MFMA GEMM ----------------
// BM=128, BN=128, BK=32; 4 waves (2x2), each 64x64 via 4x4 16x16x32 tiles; 3 MFMA per hi/lo pair.
// LDS row stride LA=40 elems (80 B): 16B-aligned rows, 2-way-max bank aliasing (free).

#define LA 40

template <int K, int AFMT>  // AFMT: 0 = planar bf16 planes, 1 = fp32 source (split on the fly)
__device__ inline void mgp(const unsigned short* __restrict__ Ah_g, const unsigned short* __restrict__ Al_g,
                           const float* __restrict__ Af_g,
                           const unsigned short* __restrict__ Wh_g, const unsigned short* __restrict__ Wl_g,
                           int m0, unsigned short* sAh, unsigned short* sAl,
                           unsigned short* sBh, unsigned short* sBl,
                           f32x4 (&acc)[4][4], int tid, int wm, int wn, int l15, int quad) {
    const int srow = tid >> 1, sc = (tid & 1) * 16;
#pragma unroll 1
    for (int kt = 0; kt < K; kt += 32) {
        __syncthreads();
        int gr = m0 + srow;
        uint4 h0 = {0, 0, 0, 0}, h1 = {0, 0, 0, 0}, l0 = {0, 0, 0, 0}, l1 = {0, 0, 0, 0};
        if (AFMT == 0) {
            if (gr < NN) {
                const uint4* ph = (const uint4*)(Ah_g + (size_t)gr * K + kt + sc);
                h0 = ph[0]; h1 = ph[1];
                const uint4* pl = (const uint4*)(Al_g + (size_t)gr * K + kt + sc);
                l0 = pl[0]; l1 = pl[1];
            }
        } else {
            if (gr < NN) {
                const float4* pf = (const float4*)(Af_g + (size_t)gr * K + kt + sc);
                float4 f0 = pf[0], f1 = pf[1], f2 = pf[2], f3 = pf[3];
                float fs[16] = {f0.x, f0.y, f0.z, f0.w, f1.x, f1.y, f1.z, f1.w,
                                f2.x, f2.y, f2.z, f2.w, f3.x, f3.y, f3.z, f3.w};
                alignas(16) unsigned short hh[16], ll[16];
#pragma unroll
                for (int i = 0; i < 16; i++) {
                    unsigned ps = pack_split(fs[i]);
                    hh[i] = (unsigned short)ps;
                    ll[i] = (unsigned short)(ps >> 16);
                }
                h0 = *(const uint4*)&hh[0]; h1 = *(const uint4*)&hh[8];
                l0 = *(const uint4*)&ll[0]; l1 = *(const uint4*)&ll[8];
            }
        }
        const uint4* qh = (const uint4*)(Wh_g + srow * K + kt + sc);
        uint4 b0 = qh[0], b1 = qh[1];
        const uint4* ql = (const uint4*)(Wl_g + srow * K + kt + sc);
        uint4 b2 = ql[0], b3 = ql[1];
        *(uint4*)(sAh + srow * LA + sc) = h0; *(uint4*)(sAh + srow * LA + sc + 8) = h1;
        *(uint4*)(sAl + srow * LA + sc) = l0; *(uint4*)(sAl + srow * LA + sc + 8) = l1;
        *(uint4*)(sBh + srow * LA + sc) = b0; *(uint4*)(sBh + srow * LA + sc + 8) = b1;
        *(uint4*)(sBl + srow * LA + sc) = b2; *(uint4*)(sBl + srow * LA + sc + 8) = b3;
        __syncthreads();
        short8 ah[4], al[4], bh[4], bl[4];
#pragma unroll
        for (int t = 0; t < 4; t++) {
            ah[t] = *(const short8*)(sAh + (wm + t * 16 + l15) * LA + quad * 8);
            al[t] = *(const short8*)(sAl + (wm + t * 16 + l15) * LA + quad * 8);
            bh[t] = *(const short8*)(sBh + (wn + t * 16 + l15) * LA + quad * 8);
            bl[t] = *(const short8*)(sBl + (wn + t * 16 + l15) * LA + quad * 8);
        }
#pragma unroll
        for (int mt = 0; mt < 4; mt++)
#pragma unroll
            for (int nt = 0; nt < 4; nt++) {
                acc[mt][nt] = __builtin_amdgcn_mfma_f32_16x16x32_bf16(ah[mt], bh[nt], acc[mt][nt], 0, 0, 0);
                acc[mt][nt] = __builtin_amdgcn_mfma_f32_16x16x32_bf16(ah[mt], bl[nt], acc[mt][nt], 0, 0, 0);
                acc[mt][nt] = __builtin_amdgcn_mfma_f32_16x16x32_bf16(al[mt], bh[nt], acc[mt][nt], 0, 0, 0);
            }
    }
}

// OMODE: 0 = fp32 C (pitch 128); 1 = planar bf16 C planes (pitch 128);
//        2 = cols<64 -> Ph bf16 (pitch 64), cols>=64 -> Qf fp32 (pitch 64)
// In-place (C planes == A planes) safe: each block writes only its own rows after all its reads.
template <int K1, int K2, int AF1, int AF2, bool RELU, int OMODE>
__global__ __launch_bounds__(256) void k_mgemm(
    const unsigned short* A1h, const unsigned short* A1l, const float* A1f,
    const unsigned short* A2h, const unsigned short* A2l, const float* A2f,
    const unsigned short* __restrict__ W1h, const unsigned short* __restrict__ W1l,
    const unsigned short* __restrict__ W2h, const unsigned short* __restrict__ W2l,
    const float* __restrict__ bias, float* Cf, unsigned short* Chi, unsigned short* Clo,
    unsigned short* Ph, float* Qf) {
    __shared__ unsigned short sAh[128 * LA], sAl[128 * LA], sBh[128 * LA], sBl[128 * LA];
    const int tid = threadIdx.x;
    const int m0 = blockIdx.x * 128;
    const int wave = tid >> 6, lane = tid & 63;
    const int wm = (wave & 1) * 64, wn = (wave >> 1) * 64;
    const int l15 = lane & 15, quad = lane >> 4;
    f32x4 acc[4][4];
#pragma unroll
    for (int i = 0; i < 4; i++)
#pragma unroll
        for (int j = 0; j < 4; j++) acc[i][j] = (f32x4){0.f, 0.f, 0.f, 0.f};

    mgp<K1, AF1>(A1h, A1l, A1f, W1h, W1l, m0, sAh, sAl, sBh, sBl, acc, tid, wm, wn, l15, quad);
    if (K2 > 0) mgp<K2, AF2>(A2h, A2l, A2f, W2h, W2l, m0, sAh, sAl, sBh, sBl, acc, tid, wm, wn, l15, quad);

#pragma unroll
    for (int mt = 0; mt < 4; mt++) {
        int rbase = m0 + wm + mt * 16 + quad * 4;
#pragma unroll
        for (int nt = 0; nt < 4; nt++) {
            int cg = wn + nt * 16 + l15;
            float bv = bias[cg];
#pragma unroll
            for (int r = 0; r < 4; r++) {
                int row = rbase + r;
                if (row < NN) {
                    float v = acc[mt][nt][r] + bv;
                    if (RELU) v = fmaxf(v, 0.f);
                    if (OMODE == 0) {
                        Cf[(size_t)row * 128 + cg] = v;
                    } else if (OMODE == 1) {
                        unsigned ps = pack_split(v);
                        Chi[(size_t)row * 128 + cg] = (unsigned short)ps;
                        Clo[(size_t)row * 128 + cg] = (unsigned short)(ps >> 16);
                    } else {
                        if (cg < 64) Ph[(size_t)row * 64 + cg] = rnb(v);
                        else Qf[(size_t)row * 64 + cg - 64] = v;
                    }
                }
            }
        }
    }
}

// ---------------- final decoder layer ----------------

__global__ __launch_bounds__(256) void k_dec2(const float* __restrict__ h, const float* __restrict__ W,
                                              const float* __restrict__ b, float* __restrict__ out) {
    int node = blockIdx.x * 4 + (threadIdx.x >> 6);
    int lane = threadIdx.x & 63;
    float2 hv = *((const float2*)(h + (size_t)node * 128) + lane);
    float d0 = hv.x * W[2 * lane] + hv.y * W[2 * lane + 1];
    float d1 = hv.x * W[128 + 2 * lane] + hv.y * W[128 + 2 * lane + 1];
    for (int off = 32; off > 0; off >>= 1) {
        d0 += __shfl_down(d0, off);
        d1 += __shfl_down(d1, off);
    }
    if (lane == 0) {
        out[(size_t)node * 2 + 0] = d0 + b[0];
        out[(size_t)node * 2 + 1] = d1 + b[1];
    }
}

// ---------------- launch ----------------

extern "C" void kernel_launch(void* const* d_in, const int* in_sizes, int n_in,
                              void* d_out, int out_size, void* d_ws, size_t ws_size,
                              hipStream_t stream) {
    const float* x   = (const float*)d_in[0];
    const int*   ei  = (const int*)d_in[1];
    const float* Wl0 = (const float*)d_in[2];
    const float* bl0 = (const float*)d_in[3];
    const float* Wr0 = (const float*)d_in[4];
    const float* Wl1 = (const float*)d_in[5];
    const float* bl1 = (const float*)d_in[6];
    const float* Wr1 = (const float*)d_in[7];
    const float* Wl2 = (const float*)d_in[8];
    const float* bl2 = (const float*)d_in[9];
    const float* Wr2 = (const float*)d_in[10];
    const float* Wd1 = (const float*)d_in[11];
    const float* bd1 = (const float*)d_in[12];
    const float* Wd2 = (const float*)d_in[13];
    const float* bd2 = (const float*)d_in[14];
    float* out = (float*)d_out;

    char* ws = (char*)d_ws;
    size_t off = 0;
    auto alloc = [&](size_t bytes) {
        char* p = ws + off;
        off = (off + bytes + 255) & ~(size_t)255;
        return p;
    };
    int*            bcnt    = (int*)alloc((size_t)NBUCK * 4);
    int*            bstart  = (int*)alloc((size_t)(NBUCK + 1) * 4);
    int*            gcur    = (int*)alloc((size_t)NBUCK * 4);
    int*            row_ptr = (int*)alloc((size_t)(NN + 1) * 4);
    float*          invd    = (float*)alloc((size_t)NN * 4);
    float*          biasPQ  = (float*)alloc(128 * 4);
    unsigned short* Wh      = (unsigned short*)alloc((size_t)73728 * 2);
    unsigned short* Wl      = (unsigned short*)alloc((size_t)73728 * 2);
    int*            col     = (int*)alloc((size_t)NE * 4);
    char*           R1      = alloc((size_t)NN * 128 * 4);  // 51.2 MB
    char*           R2      = alloc((size_t)NN * 128 * 4);  // 51.2 MB
    (void)ws_size;

    // R1 lifetime: tmp(CSR) -> [Xh 12.8 | Agg0h 12.8 | Agg0l 12.8] -> Agg1 planes (51.2)
    //              -> [Ph 12.8 | Qf 25.6] -> d1 fp32 (51.2)
    // R2 lifetime: [G0h 25.6 | G0l 25.6] -> H1 in-place -> h2 planes (25.6)
    int*            tmp   = (int*)R1;
    unsigned short* Xh    = (unsigned short*)R1;
    unsigned short* Agg0h = (unsigned short*)(R1 + 12800000);
    unsigned short* Agg0l = (unsigned short*)(R1 + 25600000);
    unsigned short* Agg1h = (unsigned short*)R1;
    unsigned short* Agg1l = (unsigned short*)(R1 + 25600000);
    unsigned short* Ph    = (unsigned short*)R1;
    float*          Qf    = (float*)(R1 + 12800000);
    float*          d1    = (float*)R1;
    unsigned short* G0h   = (unsigned short*)R2;
    unsigned short* G0l   = (unsigned short*)(R2 + 25600000);
    unsigned short* H1h   = G0h;
    unsigned short* H1l   = G0l;
    unsigned short* h2h   = (unsigned short*)R2;
    unsigned short* h2l   = (unsigned short*)(R2 + 12800000);

    const unsigned short* WL0h = Wh,         * WL0l = Wl;
    const unsigned short* WR0h = Wh + 8192,  * WR0l = Wl + 8192;
    const unsigned short* WL1h = Wh + 16384, * WL1l = Wl + 16384;
    const unsigned short* WR1h = Wh + 32768, * WR1l = Wl + 32768;
    const unsigned short* WPQh = Wh + 49152, * WPQl = Wl + 49152;
    const unsigned short* WD1h = Wh + 65536, * WD1l = Wl + 65536;

    const int* srce = ei;
    const int* dste = ei + NE;

    // CSR build (tmp aliases R1; completes before R1's next use)
    k_zero_small<<<1, 256, 0, stream>>>(bcnt, NBUCK);
    k_hist<<<400, 256, 0, stream>>>(dste, bcnt);
    k_bscan<<<1, 256, 0, stream>>>(bcnt, bstart, gcur);
    k_partition<<<P3_BLOCKS, 256, 0, stream>>>(srce, dste, gcur, tmp);
    k_bucket<<<NBUCK, 256, 0, stream>>>(tmp, bstart, row_ptr, col, invd);

    // conversions
    k_wsplit<<<289, 256, 0, stream>>>(Wl0, Wr0, Wl1, Wr1, Wl2, Wr2, Wd1, bl2, Wh, Wl, biasPQ);
    k_xhi<<<(NN * 64 / 4 + 255) / 256, 256, 0, stream>>>(x, Xh);

    const int gGemm = (NN + 127) / 128;  // 782
    const int gNode = NN / 4;            // 25000

    // Layer 0: 64 -> 128, ReLU.  A1 = Agg0 planes, A2 = x fp32 (on-the-fly split)
    k_agg64h<<<gNode, 256, 0, stream>>>(Xh, row_ptr, col, invd, Agg0h, Agg0l);
    k_mgemm<64, 64, 0, 1, true, 1><<<gGemm, 256, 0, stream>>>(
        Agg0h, Agg0l, nullptr, nullptr, nullptr, x,
        WL0h, WL0l, WR0h, WR0l, bl0, nullptr, G0h, G0l, nullptr, nullptr);

    // Layer 1: 128 -> 128, ReLU (in-place over G0 planes)
    k_agg128h<<<gNode, 256, 0, stream>>>(G0h, row_ptr, col, invd, Agg1h, Agg1l);
    k_mgemm<128, 128, 0, 0, true, 1><<<gGemm, 256, 0, stream>>>(
        Agg1h, Agg1l, nullptr, G0h, G0l, nullptr,
        WL1h, WL1l, WR1h, WR1l, bl1, nullptr, H1h, H1l, nullptr, nullptr);

    // Layer 2 (transform-before-aggregate): [P|Q] = h1 @ [Wl2;Wr2]^T + [0;bl2]
    k_mgemm<128, 0, 0, 0, false, 2><<<gGemm, 256, 0, stream>>>(
        H1h, H1l, nullptr, nullptr, nullptr, nullptr,
        WPQh, WPQl, nullptr, nullptr, biasPQ, nullptr, nullptr, nullptr, Ph, Qf);
    k_aggPh<<<gNode, 256, 0, stream>>>(Ph, Qf, row_ptr, col, invd, h2h, h2l);

    // Decoder: 64 -> 128 (ReLU) -> 2
    k_mgemm<64, 0, 0, 0, true, 0><<<gGemm, 256, 0, stream>>>(
        h2h, h2l, nullptr, nullptr, nullptr, nullptr,
        WD1h, WD1l, nullptr, nullptr, bd1, d1, nullptr, nullptr, nullptr, nullptr);
    k_dec2<<<gNode, 256, 0, stream>>>(d1, Wd2, bd2, out);
}